// Round 17
// baseline (176.689 us; speedup 1.0000x reference)
//
#include <hip/hip_runtime.h>
#include <cstdint>

#define CN (384*1024)          // 393216
#define BCN (16*CN)            // 6291456
#define EPS 1e-5f

typedef float f32x2 __attribute__((ext_vector_type(2)));
typedef float f32x4 __attribute__((ext_vector_type(4)));

// workspace layout (bytes)
#define WPT_OFF   0u           // f32[384][384] = 589824
#define WQB_OFF   589824u      // bf16-as-u16[385][384] (row 384 = zeros), ends 885504
#define QINV_OFF  1179648u
#define QOFF_OFF  (QINV_OFF + 1536u)
#define PINV_OFF  (QINV_OFF + 3072u)
#define POFF_OFF  (QINV_OFF + 4608u)
#define C0_OFF    (QINV_OFF + 6144u)
#define LCNT2_OFF 1187840u     // u8[2048 blocks][32 units], ends 1253376
#define XM_OFF    1310720u     // u64[4][16][16][384] n-packed spikes, ends 4456448
#define XMT_OFF   4456448u     // u64[4][16][1024][6] c-packed spikes, ends 7602176
#define LISTS2_OFF 7602176u    // u16[2048][32][24] offsets (idx*3), ends 10747904
#define MST_OFF   XM_OFF       // masked q-spikes u64[col][6]; reuses xm (dead after k1bc)

// ---------------- K01: fused {shortcut LIF -> bitmasks} + {weight prep + consts} ---
// blocks [0, 24576): k1 LIF work; blocks [24576, 25731): k0 prep work (independent).
__global__ __launch_bounds__(256) void k01_lif_prep(const float* __restrict__ x,
                                                    const float* __restrict__ wq,
                                                    const float* __restrict__ wp,
                                                    const float* __restrict__ qg,
                                                    const float* __restrict__ qb,
                                                    const float* __restrict__ qm,
                                                    const float* __restrict__ qv,
                                                    const float* __restrict__ pg,
                                                    const float* __restrict__ pb,
                                                    const float* __restrict__ pm,
                                                    const float* __restrict__ pv,
                                                    const float* __restrict__ bp,
                                                    unsigned long long* __restrict__ xm,
                                                    char* __restrict__ ws) {
    if (blockIdx.x < 24576) {
        int wid  = (blockIdx.x * 256 + threadIdx.x) >> 6;   // 0..98303
        int lane = threadIdx.x & 63;
        int c = wid % 384;
        int g = (wid / 384) & 15;
        int b = wid / (384 * 16);
        const float* xp = x + (size_t)b * CN + (size_t)c * 1024 + g * 64 + lane;
        float v = 0.f;
        #pragma unroll
        for (int t = 0; t < 4; ++t) {
            float xv = xp[(size_t)t * BCN];
            float h = v + (xv - v) * 0.5f;                  // v + (x - v)/tau, tau = 2
            bool s = (h >= 1.0f);
            unsigned long long m = __ballot(s);
            v = s ? 0.f : h;
            if (lane == 0) xm[(((size_t)t * 16 + b) * 16 + g) * 384 + c] = m;
        }
        return;
    }
    int bid = blockIdx.x - 24576;                    // 0..1154
    if (bid < 576) {
        int i = bid * 256 + threadIdx.x;             // 0..147455
        int c = i / 384, o = i % 384;
        ((float*)(ws + WPT_OFF))[c * 384 + o] = wp[o * 384 + c];
    } else if (bid < 1154) {
        int j = (bid - 576) * 256 + threadIdx.x;     // 0..147967
        if (j >= 147840) return;                     // 385*384
        int r = j / 384, o = j % 384;
        unsigned short v = 0;
        if (r < 384) {
            unsigned u = __float_as_uint(wq[o * 384 + r]);
            v = (unsigned short)((u + 0x7fffu + ((u >> 16) & 1u)) >> 16);  // rne bf16
        }
        ((unsigned short*)(ws + WQB_OFF))[j] = v;
    } else {
        for (int i = threadIdx.x; i < 384; i += 256) {
            float qi = qg[i] / sqrtf(qv[i] + EPS);
            ((float*)(ws + QINV_OFF))[i] = qi;
            ((float*)(ws + QOFF_OFF))[i] = qb[i] - qm[i] * qi;
            float pi = pg[i] / sqrtf(pv[i] + EPS);
            float po = pb[i] - pm[i] * pi;
            ((float*)(ws + PINV_OFF))[i] = pi;
            ((float*)(ws + POFF_OFF))[i] = po;
            ((float*)(ws + C0_OFF))[i] = bp[i] * pi + po;  // output when GEMM2 input == 0
        }
    }
}

// ---------------- K1bc: fused bit-transpose + offset-list build --------------------
// wave = (t,b,g). 6 x {load 64 row-words, 64 ballots} -> lane n holds its column's
// 6 c-packed words in registers; writes xmT (fallback path) and builds the padded
// u16 offset list + lcnt directly. Lists now shaped [2048 blocks][32 units][24].
__global__ __launch_bounds__(256) void k1bc(const unsigned long long* __restrict__ xm,
                                            unsigned long long* __restrict__ xmT,
                                            unsigned short* __restrict__ lists2,
                                            unsigned char* __restrict__ lcnt2) {
    int wid  = (blockIdx.x * 256 + threadIdx.x) >> 6;   // 0..1023 = tb*16+g
    int lane = threadIdx.x & 63;
    int g  = wid & 15;
    int tb = wid >> 4;                                  // t*16 + b
    unsigned long long T[6];
    #pragma unroll
    for (int cg = 0; cg < 6; ++cg) {
        unsigned long long W = xm[((size_t)tb * 16 + g) * 384 + cg * 64 + lane];
        unsigned long long colw = 0ull;
        #pragma unroll
        for (int k = 0; k < 64; ++k) {
            unsigned long long bk = __ballot((W >> k) & 1ull);
            if (lane == k) colw = bk;
        }
        T[cg] = colw;
    }
    const int n   = g * 64 + lane;
    const size_t col = ((size_t)tb << 10) + n;
    #pragma unroll
    for (int cg = 0; cg < 6; ++cg) xmT[col * 6 + cg] = T[cg];
    const int blockid = (tb & 15) * 128 + (n >> 3);     // b*128 + n/8
    const int un = (n & 7) * 4 + (tb >> 4);             // (n%8)*4 + t
    unsigned short* lp = lists2 + ((size_t)blockid * 32 + un) * 24;
    int k = 0;
    #pragma unroll
    for (int cg = 0; cg < 6; ++cg) {
        unsigned long long m = T[cg];
        while (m) {
            int j = __builtin_ctzll(m);
            m &= m - 1;
            if (k < 24) lp[k] = (unsigned short)((cg * 64 + j) * 3);
            ++k;
        }
    }
    int kk = k > 24 ? 24 : k;
    for (int i = kk; i < 24; ++i) lp[i] = 1152;         // 384*3 -> zero row (always pad)
    lcnt2[(size_t)blockid * 32 + un] =
        (k > 24) ? 0xFF : (unsigned char)((k + 7) >> 3);
}

// ---------------- K2: wave-per-row gather GEMM1 + BN + LIF + tail OUTPUT WRITE -----
// block = (b, nt8), 256 threads = 4 waves; wave w owns n-locals {2w, 2w+1}.
// One dwordx3 loads a whole 768B bf16 row (lane owns o = lane*6+e). Gather first
// (vmcnt FIFO store-free), epilogue, then unconditional constant write of the
// 384o x 8n tile = c0[o]; spiked tiles rewritten by k3. 2048 blocks -> finer
// generations, smaller tail, higher resident-wave count.
#define BLO(w) __uint_as_float((w) << 16)
#define BHI(w) __uint_as_float((w) & 0xFFFF0000u)
#define PK(w)  ((f32x2){BLO(w), BHI(w)})
#define RL(v, l) ((unsigned)__builtin_amdgcn_readlane((int)(v), (l)))

#define GROW8(W0, W1, W2, W3) do {                                                \
    uint3 d0_ = *(const uint3*)(wqc + ((size_t)((W0) & 0xffffu) << 8) + voff);    \
    uint3 d1_ = *(const uint3*)(wqc + ((size_t)((W0) >> 16) << 8) + voff);        \
    uint3 d2_ = *(const uint3*)(wqc + ((size_t)((W1) & 0xffffu) << 8) + voff);    \
    uint3 d3_ = *(const uint3*)(wqc + ((size_t)((W1) >> 16) << 8) + voff);        \
    uint3 d4_ = *(const uint3*)(wqc + ((size_t)((W2) & 0xffffu) << 8) + voff);    \
    uint3 d5_ = *(const uint3*)(wqc + ((size_t)((W2) >> 16) << 8) + voff);        \
    uint3 d6_ = *(const uint3*)(wqc + ((size_t)((W3) & 0xffffu) << 8) + voff);    \
    uint3 d7_ = *(const uint3*)(wqc + ((size_t)((W3) >> 16) << 8) + voff);        \
    s0 += ((PK(d0_.x) + PK(d1_.x)) + (PK(d2_.x) + PK(d3_.x)))                     \
        + ((PK(d4_.x) + PK(d5_.x)) + (PK(d6_.x) + PK(d7_.x)));                    \
    s1 += ((PK(d0_.y) + PK(d1_.y)) + (PK(d2_.y) + PK(d3_.y)))                     \
        + ((PK(d4_.y) + PK(d5_.y)) + (PK(d6_.y) + PK(d7_.y)));                    \
    s2 += ((PK(d0_.z) + PK(d1_.z)) + (PK(d2_.z) + PK(d3_.z)))                     \
        + ((PK(d4_.z) + PK(d5_.z)) + (PK(d6_.z) + PK(d7_.z)));                    \
} while (0)

__global__ __launch_bounds__(256) void k2_qpath(const char* __restrict__ wqc,
                                                const float* __restrict__ qinv_,
                                                const float* __restrict__ qoff_,
                                                const unsigned short* __restrict__ lists2,
                                                const unsigned char* __restrict__ lcnt2,
                                                const unsigned long long* __restrict__ xmT,
                                                const unsigned char* __restrict__ ak,
                                                const unsigned char* __restrict__ av,
                                                const float* __restrict__ c0,
                                                unsigned long long* __restrict__ msT,
                                                float* __restrict__ out) {
    const int tid  = threadIdx.x;
    const int lane = tid & 63;
    const int w    = tid >> 6;                   // wave 0..3
    const int nt   = blockIdx.x & 127;           // 8-wide n-tile
    const int b    = blockIdx.x >> 7;
    const int voff = lane * 12;                  // 12B per lane: o = lane*6 + e

    // lane-cache the block's gather metadata: lane u (u<32) holds unit u's 24 offsets
    const char* lb = (const char*)lists2 + (size_t)blockIdx.x * 1536 + (lane & 31) * 48;
    const uint4 L0 = *(const uint4*)lb;           // slots 0-7
    const uint4 L1 = *(const uint4*)(lb + 16);    // slots 8-15
    const uint4 L2 = *(const uint4*)(lb + 32);    // slots 16-23
    const unsigned lcv = *(const unsigned*)((const char*)lcnt2
                          + (size_t)blockIdx.x * 32 + (lane & 7) * 4);

    float qi[6], qo[6];
    #pragma unroll
    for (int e = 0; e < 6; ++e) {
        qi[e] = qinv_[lane * 6 + e];
        qo[e] = qoff_[lane * 6 + e];
    }

    #pragma unroll
    for (int i = 0; i < 2; ++i) {
        const int nl = w * 2 + i;                // n-local 0..7 (wave-uniform)
        const int n  = nt * 8 + nl;
        const unsigned lcw = RL(lcv, nl);        // 4 round-counts (one per t)
        f32x2 a0[4], a1[4], a2[4];
        // ---- phase 1: fixed 16 slots per t (compiler-scheduled batches) ----
        #pragma unroll
        for (int t = 0; t < 4; ++t) {
            const int un = nl * 4 + t;           // wave-uniform unit index, <32
            const unsigned Wa = RL(L0.x, un), Wb = RL(L0.y, un);
            const unsigned Wc = RL(L0.z, un), Wd = RL(L0.w, un);
            const unsigned We = RL(L1.x, un), Wf = RL(L1.y, un);
            const unsigned Wg = RL(L1.z, un), Wh = RL(L1.w, un);
            f32x2 s0 = {0.f, 0.f}, s1 = {0.f, 0.f}, s2 = {0.f, 0.f};
            GROW8(Wa, Wb, Wc, Wd);
            GROW8(We, Wf, Wg, Wh);
            a0[t] = s0; a1[t] = s1; a2[t] = s2;
        }
        // ---- phase 2: rare third round (k = 17..24) ----
        #pragma unroll
        for (int t = 0; t < 4; ++t) {
            if (((lcw >> (8 * t)) & 0xffu) == 3u) {
                const int un = nl * 4 + t;
                const unsigned Wa = RL(L2.x, un), Wb = RL(L2.y, un);
                const unsigned Wc = RL(L2.z, un), Wd = RL(L2.w, un);
                f32x2 s0 = a0[t], s1 = a1[t], s2 = a2[t];
                GROW8(Wa, Wb, Wc, Wd);
                a0[t] = s0; a1[t] = s1; a2[t] = s2;
            }
        }
        // ---- phase 3: overflow fallback (k > 24, ~never), recompute from zero ----
        #pragma unroll
        for (int t = 0; t < 4; ++t) {
            if (((lcw >> (8 * t)) & 0xffu) == 0xffu) {
                const int col = ((t * 16 + b) << 10) + n;
                const unsigned long long* mp = xmT + (size_t)col * 6;
                f32x2 s0 = {0.f, 0.f}, s1 = {0.f, 0.f}, s2 = {0.f, 0.f};
                #pragma unroll
                for (int cg = 0; cg < 6; ++cg) {
                    unsigned long long mm = mp[cg];
                    while (mm) {
                        int j = __builtin_ctzll(mm);
                        mm &= mm - 1;
                        uint3 dd = *(const uint3*)(wqc + (size_t)(cg * 64 + j) * 768 + voff);
                        s0 += PK(dd.x); s1 += PK(dd.y); s2 += PK(dd.z);
                    }
                }
                a0[t] = s0; a1[t] = s1; a2[t] = s2;
            }
        }
        // ---- BN + LIF + attn-mask epilogue (6 owned o's per lane) ----
        float v[6] = {0.f, 0.f, 0.f, 0.f, 0.f, 0.f};
        #pragma unroll
        for (int t = 0; t < 4; ++t) {
            const int col = ((t * 16 + b) << 10) + n;
            const float val[6] = {a0[t].x, a0[t].y, a1[t].x, a1[t].y, a2[t].x, a2[t].y};
            bool sp[6];
            #pragma unroll
            for (int e = 0; e < 6; ++e) {
                float q = val[e] * qi[e] + qo[e];
                float h = 0.5f * (v[e] + q);     // v + (q - v)/2
                bool s = (h >= 1.0f);
                v[e] = s ? 0.f : h;
                if (s) {                          // rare: attn lookup only on q-spike
                    size_t ix = ((size_t)((t * 16 + b) * 384 + lane * 6 + e) << 10) + n;
                    s = (ak[ix] != 0) && (av[ix] != 0);
                }
                sp[e] = s;
            }
            unsigned long long B0 = __ballot(sp[0]);
            unsigned long long B1 = __ballot(sp[1]);
            unsigned long long B2 = __ballot(sp[2]);
            unsigned long long B3 = __ballot(sp[3]);
            unsigned long long B4 = __ballot(sp[4]);
            unsigned long long B5 = __ballot(sp[5]);
            // word e: bit l -> o = l*6 + e
            unsigned long long sel = lane == 0 ? B0 : lane == 1 ? B1 : lane == 2 ? B2
                                   : lane == 3 ? B3 : lane == 4 ? B4 : B5;
            if (lane < 6) msT[(size_t)col * 6 + lane] = sel;
        }
    }

    // ---- tail optimistic constant write (issues after ALL loads; drains async) ----
    // tile = 384 o x 8 n floats = 768 float4 units = 3 x 256 threads.
    {
        float cv[3];
        #pragma unroll
        for (int k = 0; k < 3; ++k) cv[k] = c0[(tid + k * 256) >> 1];
        #pragma unroll
        for (int t = 0; t < 4; ++t) {
            f32x4* base4 = (f32x4*)out + (size_t)(t * 16 + b) * 384 * 256 + nt * 2;
            #pragma unroll
            for (int k = 0; k < 3; ++k) {
                int i2 = tid + k * 256;                 // 0..767
                int o = i2 >> 1, n4 = i2 & 1;           // o in [0,384), n4 in [0,2)
                float vv = cv[k];
                __builtin_nontemporal_store((f32x4){vv, vv, vv, vv},
                                            base4 + (size_t)o * 256 + n4);
            }
        }
    }
}

// ---------------- K3: slow-path guard (gather GEMM2 only where spikes exist) -------
__global__ __launch_bounds__(384) void k3_proj(const float* __restrict__ wpT,
                                               const float* __restrict__ pinv_,
                                               const float* __restrict__ poff_,
                                               const float* __restrict__ bp,
                                               const unsigned long long* __restrict__ msT,
                                               float* __restrict__ out) {
    __shared__ unsigned int wflag[6];
    const int tid = threadIdx.x;
    const int bid = blockIdx.x;
    const int g = bid & 15, b = (bid >> 4) & 15, t = bid >> 8;
    const unsigned long long* mbase = msT + ((size_t)(t * 16 + b) * 1024 + g * 64) * 6;
    unsigned long long m = mbase[tid];           // 384 words: n-local = tid/6, e = tid%6
    unsigned long long anyb = __ballot(m != 0ull);
    if ((tid & 63) == 0) wflag[tid >> 6] = (anyb != 0ull) ? 1u : 0u;
    __syncthreads();
    unsigned int any = wflag[0] | wflag[1] | wflag[2] | wflag[3] | wflag[4] | wflag[5];
    if (!any) return;                            // k2's optimistic write already correct

    // slow path (never taken on this input): per-n VGPR gather.
    // word e: bit j -> input channel j*6 + e   [matches k2's layout]
    size_t obase = (size_t)(t * 16 + b) * 384;
    float pi = pinv_[tid], po = poff_[tid], bb = bp[tid];
    for (int nl = 0; nl < 64; ++nl) {
        float acc = 0.f;
        #pragma unroll
        for (int u = 0; u < 6; ++u) {
            unsigned long long mm = mbase[nl * 6 + u];
            while (mm) {
                int j = __builtin_ctzll(mm);
                mm &= mm - 1;
                int row = j * 6 + u;
                acc += wpT[(size_t)row * 384 + tid];
            }
        }
        out[(obase + tid) * 1024 + g * 64 + nl] = (acc + bb) * pi + po;
    }
}

extern "C" void kernel_launch(void* const* d_in, const int* in_sizes, int n_in,
                              void* d_out, int out_size, void* d_ws, size_t ws_size,
                              hipStream_t stream) {
    const float* x  = (const float*)d_in[0];
    const unsigned char* ak = (const unsigned char*)d_in[1];
    const unsigned char* av = (const unsigned char*)d_in[2];
    const float* wq = (const float*)d_in[3];
    const float* qg = (const float*)d_in[4];
    const float* qb = (const float*)d_in[5];
    const float* qm = (const float*)d_in[6];
    const float* qv = (const float*)d_in[7];
    const float* wp = (const float*)d_in[8];
    const float* bp = (const float*)d_in[9];
    const float* pg = (const float*)d_in[10];
    const float* pb = (const float*)d_in[11];
    const float* pm = (const float*)d_in[12];
    const float* pv = (const float*)d_in[13];
    char* ws = (char*)d_ws;
    float* out = (float*)d_out;

    hipLaunchKernelGGL(k01_lif_prep, dim3(25731), dim3(256), 0, stream,
                       x, wq, wp, qg, qb, qm, qv, pg, pb, pm, pv, bp,
                       (unsigned long long*)(ws + XM_OFF), ws);
    hipLaunchKernelGGL(k1bc, dim3(256), dim3(256), 0, stream,
                       (const unsigned long long*)(ws + XM_OFF),
                       (unsigned long long*)(ws + XMT_OFF),
                       (unsigned short*)(ws + LISTS2_OFF),
                       (unsigned char*)(ws + LCNT2_OFF));
    hipLaunchKernelGGL(k2_qpath, dim3(2048), dim3(256), 0, stream,
                       (const char*)(ws + WQB_OFF),
                       (const float*)(ws + QINV_OFF), (const float*)(ws + QOFF_OFF),
                       (const unsigned short*)(ws + LISTS2_OFF),
                       (const unsigned char*)(ws + LCNT2_OFF),
                       (const unsigned long long*)(ws + XMT_OFF), ak, av,
                       (const float*)(ws + C0_OFF),
                       (unsigned long long*)(ws + MST_OFF), out);
    hipLaunchKernelGGL(k3_proj, dim3(1024), dim3(384), 0, stream,
                       (const float*)(ws + WPT_OFF), (const float*)(ws + PINV_OFF),
                       (const float*)(ws + POFF_OFF), bp,
                       (const unsigned long long*)(ws + MST_OFF), out);
}

// Round 18
// 93.981 us; speedup vs baseline: 1.8800x; 1.8800x over previous
//
#include <hip/hip_runtime.h>
#include <cstdint>

#define CN (384*1024)          // 393216
#define BCN (16*CN)            // 6291456
#define EPS 1e-5f

typedef float f32x2 __attribute__((ext_vector_type(2)));
typedef float f32x4 __attribute__((ext_vector_type(4)));

// workspace layout (bytes)
#define WPT_OFF   0u           // f32[384][384] = 589824
#define WQB_OFF   589824u      // bf16-as-u16[385][384] (row 384 = zeros), ends 885504
#define QINV_OFF  1179648u
#define QOFF_OFF  (QINV_OFF + 1536u)
#define PINV_OFF  (QINV_OFF + 3072u)
#define POFF_OFF  (QINV_OFF + 4608u)
#define C0_OFF    (QINV_OFF + 6144u)
#define LCNT2_OFF 1187840u     // u8[1024 blocks][64 units], ends 1253376
#define XM_OFF    1310720u     // u64[4][16][16][384] n-packed spikes, ends 4456448
#define XMT_OFF   4456448u     // u64[4][16][1024][6] c-packed spikes, ends 7602176
#define LISTS2_OFF 7602176u    // u16[1024][64][24] offsets (idx*3), ends 10747904
#define MST_OFF   XM_OFF       // masked q-spikes u64[col][6]; reuses xm (dead after k1bc)

// ---------------- K01: fused {shortcut LIF -> bitmasks} + {weight prep + consts} ---
// blocks [0, 24576): k1 LIF work; blocks [24576, 25731): k0 prep work (independent).
__global__ __launch_bounds__(256) void k01_lif_prep(const float* __restrict__ x,
                                                    const float* __restrict__ wq,
                                                    const float* __restrict__ wp,
                                                    const float* __restrict__ qg,
                                                    const float* __restrict__ qb,
                                                    const float* __restrict__ qm,
                                                    const float* __restrict__ qv,
                                                    const float* __restrict__ pg,
                                                    const float* __restrict__ pb,
                                                    const float* __restrict__ pm,
                                                    const float* __restrict__ pv,
                                                    const float* __restrict__ bp,
                                                    unsigned long long* __restrict__ xm,
                                                    char* __restrict__ ws) {
    if (blockIdx.x < 24576) {
        int wid  = (blockIdx.x * 256 + threadIdx.x) >> 6;   // 0..98303
        int lane = threadIdx.x & 63;
        int c = wid % 384;
        int g = (wid / 384) & 15;
        int b = wid / (384 * 16);
        const float* xp = x + (size_t)b * CN + (size_t)c * 1024 + g * 64 + lane;
        float v = 0.f;
        #pragma unroll
        for (int t = 0; t < 4; ++t) {
            float xv = xp[(size_t)t * BCN];
            float h = v + (xv - v) * 0.5f;                  // v + (x - v)/tau, tau = 2
            bool s = (h >= 1.0f);
            unsigned long long m = __ballot(s);
            v = s ? 0.f : h;
            if (lane == 0) xm[(((size_t)t * 16 + b) * 16 + g) * 384 + c] = m;
        }
        return;
    }
    int bid = blockIdx.x - 24576;                    // 0..1154
    if (bid < 576) {
        int i = bid * 256 + threadIdx.x;             // 0..147455
        int c = i / 384, o = i % 384;
        ((float*)(ws + WPT_OFF))[c * 384 + o] = wp[o * 384 + c];
    } else if (bid < 1154) {
        int j = (bid - 576) * 256 + threadIdx.x;     // 0..147967
        if (j >= 147840) return;                     // 385*384
        int r = j / 384, o = j % 384;
        unsigned short v = 0;
        if (r < 384) {
            unsigned u = __float_as_uint(wq[o * 384 + r]);
            v = (unsigned short)((u + 0x7fffu + ((u >> 16) & 1u)) >> 16);  // rne bf16
        }
        ((unsigned short*)(ws + WQB_OFF))[j] = v;
    } else {
        for (int i = threadIdx.x; i < 384; i += 256) {
            float qi = qg[i] / sqrtf(qv[i] + EPS);
            ((float*)(ws + QINV_OFF))[i] = qi;
            ((float*)(ws + QOFF_OFF))[i] = qb[i] - qm[i] * qi;
            float pi = pg[i] / sqrtf(pv[i] + EPS);
            float po = pb[i] - pm[i] * pi;
            ((float*)(ws + PINV_OFF))[i] = pi;
            ((float*)(ws + POFF_OFF))[i] = po;
            ((float*)(ws + C0_OFF))[i] = bp[i] * pi + po;  // output when GEMM2 input == 0
        }
    }
}

// ---------------- K1bc: fused bit-transpose + offset-list build --------------------
// wave = (t,b,g). 6 x {load 64 row-words, 64 ballots} -> lane n holds its column's
// 6 c-packed words in registers; writes xmT (fallback path) and builds the padded
// u16 offset list + lcnt directly. Lists shaped [1024 blocks][64 units][24].
__global__ __launch_bounds__(256) void k1bc(const unsigned long long* __restrict__ xm,
                                            unsigned long long* __restrict__ xmT,
                                            unsigned short* __restrict__ lists2,
                                            unsigned char* __restrict__ lcnt2) {
    int wid  = (blockIdx.x * 256 + threadIdx.x) >> 6;   // 0..1023 = tb*16+g
    int lane = threadIdx.x & 63;
    int g  = wid & 15;
    int tb = wid >> 4;                                  // t*16 + b
    unsigned long long T[6];
    #pragma unroll
    for (int cg = 0; cg < 6; ++cg) {
        unsigned long long W = xm[((size_t)tb * 16 + g) * 384 + cg * 64 + lane];
        unsigned long long colw = 0ull;
        #pragma unroll
        for (int k = 0; k < 64; ++k) {
            unsigned long long bk = __ballot((W >> k) & 1ull);
            if (lane == k) colw = bk;
        }
        T[cg] = colw;
    }
    const int n   = g * 64 + lane;
    const size_t col = ((size_t)tb << 10) + n;
    #pragma unroll
    for (int cg = 0; cg < 6; ++cg) xmT[col * 6 + cg] = T[cg];
    const int blockid = (tb & 15) * 64 + (n >> 4);      // b*64 + n/16
    const int un = (n & 15) * 4 + (tb >> 4);            // (n%16)*4 + t
    unsigned short* lp = lists2 + ((size_t)blockid * 64 + un) * 24;
    int k = 0;
    #pragma unroll
    for (int cg = 0; cg < 6; ++cg) {
        unsigned long long m = T[cg];
        while (m) {
            int j = __builtin_ctzll(m);
            m &= m - 1;
            if (k < 24) lp[k] = (unsigned short)((cg * 64 + j) * 3);
            ++k;
        }
    }
    int kk = k > 24 ? 24 : k;
    for (int i = kk; i < 24; ++i) lp[i] = 1152;         // 384*3 -> zero row (always pad)
    lcnt2[(size_t)blockid * 64 + un] =
        (k > 24) ? 0xFF : (unsigned char)((k + 7) >> 3);
}

// ---------------- K2: wave-per-row gather GEMM1 + fused per-t BN/LIF + tail write --
// block = (b, nt16), 512 threads = 8 waves; wave w owns n-locals {2w, 2w+1}.
// One dwordx3 loads a whole 768B bf16 row (lane owns o = lane*6+e). Epilogue is
// fused per-t (only v[6] carried) -> no a[4] accumulator arrays -> VGPR <= 64 ->
// 8 waves/SIMD residency. Tail: unconditional constant write out = c0[o] (64B
// chunks); spiked tiles rewritten by k3.
#define BLO(w) __uint_as_float((w) << 16)
#define BHI(w) __uint_as_float((w) & 0xFFFF0000u)
#define PK(w)  ((f32x2){BLO(w), BHI(w)})
#define RL(v, l) ((unsigned)__builtin_amdgcn_readlane((int)(v), (l)))

#define GROW8(W0, W1, W2, W3) do {                                                \
    uint3 d0_ = *(const uint3*)(wqc + ((size_t)((W0) & 0xffffu) << 8) + voff);    \
    uint3 d1_ = *(const uint3*)(wqc + ((size_t)((W0) >> 16) << 8) + voff);        \
    uint3 d2_ = *(const uint3*)(wqc + ((size_t)((W1) & 0xffffu) << 8) + voff);    \
    uint3 d3_ = *(const uint3*)(wqc + ((size_t)((W1) >> 16) << 8) + voff);        \
    uint3 d4_ = *(const uint3*)(wqc + ((size_t)((W2) & 0xffffu) << 8) + voff);    \
    uint3 d5_ = *(const uint3*)(wqc + ((size_t)((W2) >> 16) << 8) + voff);        \
    uint3 d6_ = *(const uint3*)(wqc + ((size_t)((W3) & 0xffffu) << 8) + voff);    \
    uint3 d7_ = *(const uint3*)(wqc + ((size_t)((W3) >> 16) << 8) + voff);        \
    s0 += ((PK(d0_.x) + PK(d1_.x)) + (PK(d2_.x) + PK(d3_.x)))                     \
        + ((PK(d4_.x) + PK(d5_.x)) + (PK(d6_.x) + PK(d7_.x)));                    \
    s1 += ((PK(d0_.y) + PK(d1_.y)) + (PK(d2_.y) + PK(d3_.y)))                     \
        + ((PK(d4_.y) + PK(d5_.y)) + (PK(d6_.y) + PK(d7_.y)));                    \
    s2 += ((PK(d0_.z) + PK(d1_.z)) + (PK(d2_.z) + PK(d3_.z)))                     \
        + ((PK(d4_.z) + PK(d5_.z)) + (PK(d6_.z) + PK(d7_.z)));                    \
} while (0)

__global__ __launch_bounds__(512) void k2_qpath(const char* __restrict__ wqc,
                                                const float* __restrict__ qinv_,
                                                const float* __restrict__ qoff_,
                                                const unsigned short* __restrict__ lists2,
                                                const unsigned char* __restrict__ lcnt2,
                                                const unsigned long long* __restrict__ xmT,
                                                const unsigned char* __restrict__ ak,
                                                const unsigned char* __restrict__ av,
                                                const float* __restrict__ c0,
                                                unsigned long long* __restrict__ msT,
                                                float* __restrict__ out) {
    const int tid  = threadIdx.x;
    const int lane = tid & 63;
    const int w    = tid >> 6;                   // wave 0..7
    const int nt   = blockIdx.x & 63;
    const int b    = blockIdx.x >> 6;
    const int voff = lane * 12;                  // 12B per lane: o = lane*6 + e

    // lane-cache the block's gather metadata: lane u holds unit u's 24 u16 offsets
    const char* lb = (const char*)lists2 + (size_t)blockIdx.x * 3072 + lane * 48;
    const uint4 L0 = *(const uint4*)lb;           // slots 0-7
    const uint4 L1 = *(const uint4*)(lb + 16);    // slots 8-15
    const uint4 L2 = *(const uint4*)(lb + 32);    // slots 16-23
    const unsigned lcv = *(const unsigned*)((const char*)lcnt2
                          + (size_t)blockIdx.x * 64 + (lane & 15) * 4);

    float qi[6], qo[6];
    #pragma unroll
    for (int e = 0; e < 6; ++e) {
        qi[e] = qinv_[lane * 6 + e];
        qo[e] = qoff_[lane * 6 + e];
    }

    #pragma unroll
    for (int i = 0; i < 2; ++i) {
        const int nl = w * 2 + i;                // n-local 0..15 (wave-uniform)
        const int n  = nt * 16 + nl;
        const unsigned lcw = RL(lcv, nl);        // 4 round-counts (one per t)
        float v[6] = {0.f, 0.f, 0.f, 0.f, 0.f, 0.f};
        #pragma unroll
        for (int t = 0; t < 4; ++t) {
            const int un = nl * 4 + t;           // wave-uniform unit index
            const unsigned r_ = (lcw >> (8 * t)) & 0xffu;
            f32x2 s0 = {0.f, 0.f}, s1 = {0.f, 0.f}, s2 = {0.f, 0.f};
            // ---- 16 unconditional slots (padded; zero row absorbs empties) ----
            {
                const unsigned Wa = RL(L0.x, un), Wb = RL(L0.y, un);
                const unsigned Wc = RL(L0.z, un), Wd = RL(L0.w, un);
                const unsigned We = RL(L1.x, un), Wf = RL(L1.y, un);
                const unsigned Wg = RL(L1.z, un), Wh = RL(L1.w, un);
                GROW8(Wa, Wb, Wc, Wd);
                GROW8(We, Wf, Wg, Wh);
            }
            // ---- rare third round (k = 17..24) ----
            if (r_ == 3u) {
                const unsigned Wa = RL(L2.x, un), Wb = RL(L2.y, un);
                const unsigned Wc = RL(L2.z, un), Wd = RL(L2.w, un);
                GROW8(Wa, Wb, Wc, Wd);
            }
            // ---- overflow fallback (k > 24, ~never): recompute from zero ----
            if (r_ == 0xffu) {
                const int colf = ((t * 16 + b) << 10) + n;
                const unsigned long long* mp = xmT + (size_t)colf * 6;
                s0 = (f32x2){0.f, 0.f}; s1 = (f32x2){0.f, 0.f}; s2 = (f32x2){0.f, 0.f};
                #pragma unroll
                for (int cg = 0; cg < 6; ++cg) {
                    unsigned long long mm = mp[cg];
                    while (mm) {
                        int j = __builtin_ctzll(mm);
                        mm &= mm - 1;
                        uint3 dd = *(const uint3*)(wqc + (size_t)(cg * 64 + j) * 768 + voff);
                        s0 += PK(dd.x); s1 += PK(dd.y); s2 += PK(dd.z);
                    }
                }
            }
            // ---- fused BN + LIF + attn-mask epilogue for this t ----
            const int col = ((t * 16 + b) << 10) + n;
            const float val[6] = {s0.x, s0.y, s1.x, s1.y, s2.x, s2.y};
            bool sp[6];
            #pragma unroll
            for (int e = 0; e < 6; ++e) {
                float q = val[e] * qi[e] + qo[e];
                float h = 0.5f * (v[e] + q);     // v + (q - v)/2
                bool s = (h >= 1.0f);
                v[e] = s ? 0.f : h;
                if (s) {                          // rare: attn lookup only on q-spike
                    size_t ix = ((size_t)((t * 16 + b) * 384 + lane * 6 + e) << 10) + n;
                    s = (ak[ix] != 0) && (av[ix] != 0);
                }
                sp[e] = s;
            }
            unsigned long long B0 = __ballot(sp[0]);
            unsigned long long B1 = __ballot(sp[1]);
            unsigned long long B2 = __ballot(sp[2]);
            unsigned long long B3 = __ballot(sp[3]);
            unsigned long long B4 = __ballot(sp[4]);
            unsigned long long B5 = __ballot(sp[5]);
            // word e: bit l -> o = l*6 + e
            unsigned long long sel = lane == 0 ? B0 : lane == 1 ? B1 : lane == 2 ? B2
                                   : lane == 3 ? B3 : lane == 4 ? B4 : B5;
            if (lane < 6) msT[(size_t)col * 6 + lane] = sel;
        }
    }

    // ---- tail optimistic constant write (issues after ALL loads; drains async) ----
    // tile = 384 o x 16 n floats = 1536 float4 units = 3 x 512 threads, 64B chunks.
    {
        float cv[3];
        #pragma unroll
        for (int k = 0; k < 3; ++k) cv[k] = c0[(tid + k * 512) >> 2];
        #pragma unroll
        for (int t = 0; t < 4; ++t) {
            f32x4* base4 = (f32x4*)out + (size_t)(t * 16 + b) * 384 * 256 + nt * 4;
            #pragma unroll
            for (int k = 0; k < 3; ++k) {
                int i2 = tid + k * 512;                 // 0..1535
                int o = i2 >> 2, n4 = i2 & 3;           // o in [0,384), n4 in [0,4)
                float vv = cv[k];
                __builtin_nontemporal_store((f32x4){vv, vv, vv, vv},
                                            base4 + (size_t)o * 256 + n4);
            }
        }
    }
}

// ---------------- K3: slow-path guard (gather GEMM2 only where spikes exist) -------
__global__ __launch_bounds__(384) void k3_proj(const float* __restrict__ wpT,
                                               const float* __restrict__ pinv_,
                                               const float* __restrict__ poff_,
                                               const float* __restrict__ bp,
                                               const unsigned long long* __restrict__ msT,
                                               float* __restrict__ out) {
    __shared__ unsigned int wflag[6];
    const int tid = threadIdx.x;
    const int bid = blockIdx.x;
    const int g = bid & 15, b = (bid >> 4) & 15, t = bid >> 8;
    const unsigned long long* mbase = msT + ((size_t)(t * 16 + b) * 1024 + g * 64) * 6;
    unsigned long long m = mbase[tid];           // 384 words: n-local = tid/6, e = tid%6
    unsigned long long anyb = __ballot(m != 0ull);
    if ((tid & 63) == 0) wflag[tid >> 6] = (anyb != 0ull) ? 1u : 0u;
    __syncthreads();
    unsigned int any = wflag[0] | wflag[1] | wflag[2] | wflag[3] | wflag[4] | wflag[5];
    if (!any) return;                            // k2's optimistic write already correct

    // slow path (never taken on this input): per-n VGPR gather.
    // word e: bit j -> input channel j*6 + e   [matches k2's layout]
    size_t obase = (size_t)(t * 16 + b) * 384;
    float pi = pinv_[tid], po = poff_[tid], bb = bp[tid];
    for (int nl = 0; nl < 64; ++nl) {
        float acc = 0.f;
        #pragma unroll
        for (int u = 0; u < 6; ++u) {
            unsigned long long mm = mbase[nl * 6 + u];
            while (mm) {
                int j = __builtin_ctzll(mm);
                mm &= mm - 1;
                int row = j * 6 + u;
                acc += wpT[(size_t)row * 384 + tid];
            }
        }
        out[(obase + tid) * 1024 + g * 64 + nl] = (acc + bb) * pi + po;
    }
}

extern "C" void kernel_launch(void* const* d_in, const int* in_sizes, int n_in,
                              void* d_out, int out_size, void* d_ws, size_t ws_size,
                              hipStream_t stream) {
    const float* x  = (const float*)d_in[0];
    const unsigned char* ak = (const unsigned char*)d_in[1];
    const unsigned char* av = (const unsigned char*)d_in[2];
    const float* wq = (const float*)d_in[3];
    const float* qg = (const float*)d_in[4];
    const float* qb = (const float*)d_in[5];
    const float* qm = (const float*)d_in[6];
    const float* qv = (const float*)d_in[7];
    const float* wp = (const float*)d_in[8];
    const float* bp = (const float*)d_in[9];
    const float* pg = (const float*)d_in[10];
    const float* pb = (const float*)d_in[11];
    const float* pm = (const float*)d_in[12];
    const float* pv = (const float*)d_in[13];
    char* ws = (char*)d_ws;
    float* out = (float*)d_out;

    hipLaunchKernelGGL(k01_lif_prep, dim3(25731), dim3(256), 0, stream,
                       x, wq, wp, qg, qb, qm, qv, pg, pb, pm, pv, bp,
                       (unsigned long long*)(ws + XM_OFF), ws);
    hipLaunchKernelGGL(k1bc, dim3(256), dim3(256), 0, stream,
                       (const unsigned long long*)(ws + XM_OFF),
                       (unsigned long long*)(ws + XMT_OFF),
                       (unsigned short*)(ws + LISTS2_OFF),
                       (unsigned char*)(ws + LCNT2_OFF));
    hipLaunchKernelGGL(k2_qpath, dim3(1024), dim3(512), 0, stream,
                       (const char*)(ws + WQB_OFF),
                       (const float*)(ws + QINV_OFF), (const float*)(ws + QOFF_OFF),
                       (const unsigned short*)(ws + LISTS2_OFF),
                       (const unsigned char*)(ws + LCNT2_OFF),
                       (const unsigned long long*)(ws + XMT_OFF), ak, av,
                       (const float*)(ws + C0_OFF),
                       (unsigned long long*)(ws + MST_OFF), out);
    hipLaunchKernelGGL(k3_proj, dim3(1024), dim3(384), 0, stream,
                       (const float*)(ws + WPT_OFF), (const float*)(ws + PINV_OFF),
                       (const float*)(ws + POFF_OFF), bp,
                       (const unsigned long long*)(ws + MST_OFF), out);
}

// Round 19
// 91.392 us; speedup vs baseline: 1.9333x; 1.0283x over previous
//
#include <hip/hip_runtime.h>
#include <cstdint>

#define CN (384*1024)          // 393216
#define BCN (16*CN)            // 6291456
#define EPS 1e-5f

typedef float f32x2 __attribute__((ext_vector_type(2)));
typedef float f32x4 __attribute__((ext_vector_type(4)));

// workspace layout (bytes)
#define WPT_OFF   0u           // f32[384][384] = 589824
#define WQB_OFF   589824u      // bf16-as-u16[385][384] (row 384 = zeros), ends 885504
#define QINV_OFF  1179648u
#define QOFF_OFF  (QINV_OFF + 1536u)
#define PINV_OFF  (QINV_OFF + 3072u)
#define POFF_OFF  (QINV_OFF + 4608u)
#define C0_OFF    (QINV_OFF + 6144u)
#define LCNT2_OFF 1187840u     // u8[1024 blocks][64 units], ends 1253376
#define ROWMAX_OFF 1253376u    // f32[384] max_o |bf16(wq[o,r])|, ends 1254912
#define MAXQ_OFF  1254912u     // f32[2] = {max|qi|, max|qo|}
#define XM_OFF    1310720u     // u64[4][16][16][384] n-packed spikes, ends 4456448
#define XMT_OFF   4456448u     // u64[4][16][1024][6] c-packed spikes, ends 7602176
#define LISTS2_OFF 7602176u    // u16[1024][64][24] offsets (idx*3), ends 10747904
#define ABND_OFF  10747904u    // u8[1024][64] quantized unit bounds A*64 (ceil), ends 10813440
#define MST_OFF   XM_OFF       // masked q-spikes u64[col][6]; reuses xm (dead after k1bc)

// ---------------- K01: fused {LIF -> bitmasks} + {weight prep + consts + rowmax} ---
// blocks [0,24576): LIF; [24576,25730): wpT/wqb; [25730]: consts+maxq; [25731,25737): rowmax.
__global__ __launch_bounds__(256) void k01_lif_prep(const float* __restrict__ x,
                                                    const float* __restrict__ wq,
                                                    const float* __restrict__ wp,
                                                    const float* __restrict__ qg,
                                                    const float* __restrict__ qb,
                                                    const float* __restrict__ qm,
                                                    const float* __restrict__ qv,
                                                    const float* __restrict__ pg,
                                                    const float* __restrict__ pb,
                                                    const float* __restrict__ pm,
                                                    const float* __restrict__ pv,
                                                    const float* __restrict__ bp,
                                                    unsigned long long* __restrict__ xm,
                                                    char* __restrict__ ws) {
    if (blockIdx.x < 24576) {
        int wid  = (blockIdx.x * 256 + threadIdx.x) >> 6;   // 0..98303
        int lane = threadIdx.x & 63;
        int c = wid % 384;
        int g = (wid / 384) & 15;
        int b = wid / (384 * 16);
        const float* xp = x + (size_t)b * CN + (size_t)c * 1024 + g * 64 + lane;
        float v = 0.f;
        #pragma unroll
        for (int t = 0; t < 4; ++t) {
            float xv = xp[(size_t)t * BCN];
            float h = v + (xv - v) * 0.5f;                  // v + (x - v)/tau, tau = 2
            bool s = (h >= 1.0f);
            unsigned long long m = __ballot(s);
            v = s ? 0.f : h;
            if (lane == 0) xm[(((size_t)t * 16 + b) * 16 + g) * 384 + c] = m;
        }
        return;
    }
    int bid = blockIdx.x - 24576;                    // 0..1160
    if (bid < 576) {
        int i = bid * 256 + threadIdx.x;             // 0..147455
        int c = i / 384, o = i % 384;
        ((float*)(ws + WPT_OFF))[c * 384 + o] = wp[o * 384 + c];
    } else if (bid < 1154) {
        int j = (bid - 576) * 256 + threadIdx.x;     // 0..147967
        if (j >= 147840) return;                     // 385*384
        int r = j / 384, o = j % 384;
        unsigned short v = 0;
        if (r < 384) {
            unsigned u = __float_as_uint(wq[o * 384 + r]);
            v = (unsigned short)((u + 0x7fffu + ((u >> 16) & 1u)) >> 16);  // rne bf16
        }
        ((unsigned short*)(ws + WQB_OFF))[j] = v;
    } else if (bid == 1154) {
        __shared__ float smi[256], smo[256];
        float mi = 0.f, mo = 0.f;
        for (int i = threadIdx.x; i < 384; i += 256) {
            float qi = qg[i] / sqrtf(qv[i] + EPS);
            ((float*)(ws + QINV_OFF))[i] = qi;
            float qov = qb[i] - qm[i] * qi;
            ((float*)(ws + QOFF_OFF))[i] = qov;
            float pi = pg[i] / sqrtf(pv[i] + EPS);
            float po = pb[i] - pm[i] * pi;
            ((float*)(ws + PINV_OFF))[i] = pi;
            ((float*)(ws + POFF_OFF))[i] = po;
            ((float*)(ws + C0_OFF))[i] = bp[i] * pi + po;  // output when GEMM2 input == 0
            mi = fmaxf(mi, fabsf(qi));
            mo = fmaxf(mo, fabsf(qov));
        }
        smi[threadIdx.x] = mi; smo[threadIdx.x] = mo;
        __syncthreads();
        for (int s = 128; s > 0; s >>= 1) {
            if (threadIdx.x < s) {
                smi[threadIdx.x] = fmaxf(smi[threadIdx.x], smi[threadIdx.x + s]);
                smo[threadIdx.x] = fmaxf(smo[threadIdx.x], smo[threadIdx.x + s]);
            }
            __syncthreads();
        }
        if (threadIdx.x == 0) {
            ((float*)(ws + MAXQ_OFF))[0] = smi[0];
            ((float*)(ws + MAXQ_OFF))[1] = smo[0];
        }
    } else {
        // rowmax: 6 blocks x 64 rows; thread = (row-local<<2)|quarter, 96 o's each
        __shared__ float sm[256];
        int rblk = bid - 1155;                       // 0..5
        int row = rblk * 64 + (threadIdx.x >> 2);
        int qd  = threadIdx.x & 3;
        float m = 0.f;
        for (int o = qd * 96; o < qd * 96 + 96; ++o) {
            unsigned u = __float_as_uint(wq[(size_t)o * 384 + row]);
            unsigned bbits = (u + 0x7fffu + ((u >> 16) & 1u)) >> 16;   // rne bf16
            m = fmaxf(m, __uint_as_float((bbits & 0x7fffu) << 16));    // |bf16|
        }
        sm[threadIdx.x] = m;
        __syncthreads();
        if (qd == 0) {
            float r0 = fmaxf(fmaxf(sm[threadIdx.x], sm[threadIdx.x + 1]),
                             fmaxf(sm[threadIdx.x + 2], sm[threadIdx.x + 3]));
            ((float*)(ws + ROWMAX_OFF))[row] = r0;
        }
    }
}

// ---------------- K1bc: fused bit-transpose + offset-list + unit-bound build -------
// wave = (t,b,g). 64 ballots x6 -> lane n holds its column's 6 c-packed words;
// writes xmT, builds padded u16 offset list + lcnt, and the quantized unit bound
// A = maxqi * sum(rowmax[list]) + maxqo (ceil to 1/64 units, sat 255 -> never skip).
__global__ __launch_bounds__(256) void k1bc(const unsigned long long* __restrict__ xm,
                                            const float* __restrict__ rowmaxp,
                                            const float* __restrict__ maxqp,
                                            unsigned long long* __restrict__ xmT,
                                            unsigned short* __restrict__ lists2,
                                            unsigned char* __restrict__ lcnt2,
                                            unsigned char* __restrict__ abnd) {
    int wid  = (blockIdx.x * 256 + threadIdx.x) >> 6;   // 0..1023 = tb*16+g
    int lane = threadIdx.x & 63;
    int g  = wid & 15;
    int tb = wid >> 4;                                  // t*16 + b
    unsigned long long T[6];
    #pragma unroll
    for (int cg = 0; cg < 6; ++cg) {
        unsigned long long W = xm[((size_t)tb * 16 + g) * 384 + cg * 64 + lane];
        unsigned long long colw = 0ull;
        #pragma unroll
        for (int k = 0; k < 64; ++k) {
            unsigned long long bk = __ballot((W >> k) & 1ull);
            if (lane == k) colw = bk;
        }
        T[cg] = colw;
    }
    const int n   = g * 64 + lane;
    const size_t col = ((size_t)tb << 10) + n;
    #pragma unroll
    for (int cg = 0; cg < 6; ++cg) xmT[col * 6 + cg] = T[cg];
    const int blockid = (tb & 15) * 64 + (n >> 4);      // b*64 + n/16
    const int un = (n & 15) * 4 + (tb >> 4);            // (n%16)*4 + t
    unsigned short* lp = lists2 + ((size_t)blockid * 64 + un) * 24;
    int k = 0;
    float S = 0.f;
    #pragma unroll
    for (int cg = 0; cg < 6; ++cg) {
        unsigned long long m = T[cg];
        while (m) {
            int j = __builtin_ctzll(m);
            m &= m - 1;
            S += rowmaxp[cg * 64 + j];
            if (k < 24) lp[k] = (unsigned short)((cg * 64 + j) * 3);
            ++k;
        }
    }
    int kk = k > 24 ? 24 : k;
    for (int i = kk; i < 24; ++i) lp[i] = 1152;         // 384*3 -> zero row (always pad)
    lcnt2[(size_t)blockid * 64 + un] =
        (k > 24) ? 0xFF : (unsigned char)((k + 7) >> 3);
    float A = maxqp[0] * S + maxqp[1];
    int aq = (int)ceilf(A * 64.f);
    abnd[(size_t)blockid * 64 + un] = (unsigned char)(aq > 255 ? 255 : (aq < 0 ? 0 : aq));
}

// ---------------- K2: bound-skip + wave-per-row gather GEMM1 + fused BN/LIF --------
// block = (b, nt16), 512 threads = 8 waves; wave w owns n-locals {2w, 2w+1}.
// Per column: LIF interval recursion on the quantized unit bounds proves ~85% of
// columns spike-free -> write msT=0, skip the gather entirely (tail write is exact).
// Else: dwordx3 row gather (lane owns o=lane*6+e), fused per-t BN/LIF/mask epilogue.
// Tail: unconditional constant write out = c0[o]; spiked tiles rewritten by k3.
#define BLO(w) __uint_as_float((w) << 16)
#define BHI(w) __uint_as_float((w) & 0xFFFF0000u)
#define PK(w)  ((f32x2){BLO(w), BHI(w)})
#define RL(v, l) ((unsigned)__builtin_amdgcn_readlane((int)(v), (l)))

#define GROW8(W0, W1, W2, W3) do {                                                \
    uint3 d0_ = *(const uint3*)(wqc + ((size_t)((W0) & 0xffffu) << 8) + voff);    \
    uint3 d1_ = *(const uint3*)(wqc + ((size_t)((W0) >> 16) << 8) + voff);        \
    uint3 d2_ = *(const uint3*)(wqc + ((size_t)((W1) & 0xffffu) << 8) + voff);    \
    uint3 d3_ = *(const uint3*)(wqc + ((size_t)((W1) >> 16) << 8) + voff);        \
    uint3 d4_ = *(const uint3*)(wqc + ((size_t)((W2) & 0xffffu) << 8) + voff);    \
    uint3 d5_ = *(const uint3*)(wqc + ((size_t)((W2) >> 16) << 8) + voff);        \
    uint3 d6_ = *(const uint3*)(wqc + ((size_t)((W3) & 0xffffu) << 8) + voff);    \
    uint3 d7_ = *(const uint3*)(wqc + ((size_t)((W3) >> 16) << 8) + voff);        \
    s0 += ((PK(d0_.x) + PK(d1_.x)) + (PK(d2_.x) + PK(d3_.x)))                     \
        + ((PK(d4_.x) + PK(d5_.x)) + (PK(d6_.x) + PK(d7_.x)));                    \
    s1 += ((PK(d0_.y) + PK(d1_.y)) + (PK(d2_.y) + PK(d3_.y)))                     \
        + ((PK(d4_.y) + PK(d5_.y)) + (PK(d6_.y) + PK(d7_.y)));                    \
    s2 += ((PK(d0_.z) + PK(d1_.z)) + (PK(d2_.z) + PK(d3_.z)))                     \
        + ((PK(d4_.z) + PK(d5_.z)) + (PK(d6_.z) + PK(d7_.z)));                    \
} while (0)

__global__ __launch_bounds__(512) void k2_qpath(const char* __restrict__ wqc,
                                                const float* __restrict__ qinv_,
                                                const float* __restrict__ qoff_,
                                                const unsigned short* __restrict__ lists2,
                                                const unsigned char* __restrict__ lcnt2,
                                                const unsigned char* __restrict__ abnd,
                                                const unsigned long long* __restrict__ xmT,
                                                const unsigned char* __restrict__ ak,
                                                const unsigned char* __restrict__ av,
                                                const float* __restrict__ c0,
                                                unsigned long long* __restrict__ msT,
                                                float* __restrict__ out) {
    const int tid  = threadIdx.x;
    const int lane = tid & 63;
    const int w    = tid >> 6;                   // wave 0..7
    const int nt   = blockIdx.x & 63;
    const int b    = blockIdx.x >> 6;
    const int voff = lane * 12;                  // 12B per lane: o = lane*6 + e

    // lane-cache the block's gather metadata: lane u holds unit u's 24 u16 offsets
    const char* lb = (const char*)lists2 + (size_t)blockIdx.x * 3072 + lane * 48;
    const uint4 L0 = *(const uint4*)lb;           // slots 0-7
    const uint4 L1 = *(const uint4*)(lb + 16);    // slots 8-15
    const uint4 L2 = *(const uint4*)(lb + 32);    // slots 16-23
    const unsigned lcv = *(const unsigned*)((const char*)lcnt2
                          + (size_t)blockIdx.x * 64 + (lane & 15) * 4);
    const unsigned abv = *(const unsigned*)((const char*)abnd
                          + (size_t)blockIdx.x * 64 + (lane & 15) * 4);

    float qi[6], qo[6];
    #pragma unroll
    for (int e = 0; e < 6; ++e) {
        qi[e] = qinv_[lane * 6 + e];
        qo[e] = qoff_[lane * 6 + e];
    }

    #pragma unroll
    for (int i = 0; i < 2; ++i) {
        const int nl = w * 2 + i;                // n-local 0..15 (wave-uniform)
        const int n  = nt * 16 + nl;
        const unsigned abw = RL(abv, nl);        // 4 quantized unit bounds
        // ---- LIF interval recursion on bounds: prove no spike at any t ----
        float hb = 0.f;
        bool skip = true;
        #pragma unroll
        for (int t = 0; t < 4; ++t) {
            float A = (float)((abw >> (8 * t)) & 0xffu) * 0.015625f + 0.015625f;
            hb = 0.5f * (hb + A);
            skip = skip && (hb < 1.0f);
        }
        if (skip) {                               // provably spike-free column
            if (lane < 6) {
                #pragma unroll
                for (int t = 0; t < 4; ++t)
                    msT[(size_t)(((t * 16 + b) << 10) + n) * 6 + lane] = 0ull;
            }
            continue;
        }
        const unsigned lcw = RL(lcv, nl);        // 4 round-counts (one per t)
        float v[6] = {0.f, 0.f, 0.f, 0.f, 0.f, 0.f};
        #pragma unroll
        for (int t = 0; t < 4; ++t) {
            const int un = nl * 4 + t;           // wave-uniform unit index
            const unsigned r_ = (lcw >> (8 * t)) & 0xffu;
            f32x2 s0 = {0.f, 0.f}, s1 = {0.f, 0.f}, s2 = {0.f, 0.f};
            // ---- 16 unconditional slots (padded; zero row absorbs empties) ----
            {
                const unsigned Wa = RL(L0.x, un), Wb = RL(L0.y, un);
                const unsigned Wc = RL(L0.z, un), Wd = RL(L0.w, un);
                const unsigned We = RL(L1.x, un), Wf = RL(L1.y, un);
                const unsigned Wg = RL(L1.z, un), Wh = RL(L1.w, un);
                GROW8(Wa, Wb, Wc, Wd);
                GROW8(We, Wf, Wg, Wh);
            }
            // ---- rare third round (k = 17..24) ----
            if (r_ == 3u) {
                const unsigned Wa = RL(L2.x, un), Wb = RL(L2.y, un);
                const unsigned Wc = RL(L2.z, un), Wd = RL(L2.w, un);
                GROW8(Wa, Wb, Wc, Wd);
            }
            // ---- overflow fallback (k > 24, ~never): recompute from zero ----
            if (r_ == 0xffu) {
                const int colf = ((t * 16 + b) << 10) + n;
                const unsigned long long* mp = xmT + (size_t)colf * 6;
                s0 = (f32x2){0.f, 0.f}; s1 = (f32x2){0.f, 0.f}; s2 = (f32x2){0.f, 0.f};
                #pragma unroll
                for (int cg = 0; cg < 6; ++cg) {
                    unsigned long long mm = mp[cg];
                    while (mm) {
                        int j = __builtin_ctzll(mm);
                        mm &= mm - 1;
                        uint3 dd = *(const uint3*)(wqc + (size_t)(cg * 64 + j) * 768 + voff);
                        s0 += PK(dd.x); s1 += PK(dd.y); s2 += PK(dd.z);
                    }
                }
            }
            // ---- fused BN + LIF + attn-mask epilogue for this t ----
            const int col = ((t * 16 + b) << 10) + n;
            const float val[6] = {s0.x, s0.y, s1.x, s1.y, s2.x, s2.y};
            bool sp[6];
            #pragma unroll
            for (int e = 0; e < 6; ++e) {
                float q = val[e] * qi[e] + qo[e];
                float h = 0.5f * (v[e] + q);     // v + (q - v)/2
                bool s = (h >= 1.0f);
                v[e] = s ? 0.f : h;
                if (s) {                          // rare: attn lookup only on q-spike
                    size_t ix = ((size_t)((t * 16 + b) * 384 + lane * 6 + e) << 10) + n;
                    s = (ak[ix] != 0) && (av[ix] != 0);
                }
                sp[e] = s;
            }
            unsigned long long B0 = __ballot(sp[0]);
            unsigned long long B1 = __ballot(sp[1]);
            unsigned long long B2 = __ballot(sp[2]);
            unsigned long long B3 = __ballot(sp[3]);
            unsigned long long B4 = __ballot(sp[4]);
            unsigned long long B5 = __ballot(sp[5]);
            // word e: bit l -> o = l*6 + e
            unsigned long long sel = lane == 0 ? B0 : lane == 1 ? B1 : lane == 2 ? B2
                                   : lane == 3 ? B3 : lane == 4 ? B4 : B5;
            if (lane < 6) msT[(size_t)col * 6 + lane] = sel;
        }
    }

    // ---- tail optimistic constant write (issues after ALL loads; drains async) ----
    // tile = 384 o x 16 n floats = 1536 float4 units = 3 x 512 threads, 64B chunks.
    {
        float cv[3];
        #pragma unroll
        for (int k = 0; k < 3; ++k) cv[k] = c0[(tid + k * 512) >> 2];
        #pragma unroll
        for (int t = 0; t < 4; ++t) {
            f32x4* base4 = (f32x4*)out + (size_t)(t * 16 + b) * 384 * 256 + nt * 4;
            #pragma unroll
            for (int k = 0; k < 3; ++k) {
                int i2 = tid + k * 512;                 // 0..1535
                int o = i2 >> 2, n4 = i2 & 3;           // o in [0,384), n4 in [0,4)
                float vv = cv[k];
                __builtin_nontemporal_store((f32x4){vv, vv, vv, vv},
                                            base4 + (size_t)o * 256 + n4);
            }
        }
    }
}

// ---------------- K3: slow-path guard (gather GEMM2 only where spikes exist) -------
__global__ __launch_bounds__(384) void k3_proj(const float* __restrict__ wpT,
                                               const float* __restrict__ pinv_,
                                               const float* __restrict__ poff_,
                                               const float* __restrict__ bp,
                                               const unsigned long long* __restrict__ msT,
                                               float* __restrict__ out) {
    __shared__ unsigned int wflag[6];
    const int tid = threadIdx.x;
    const int bid = blockIdx.x;
    const int g = bid & 15, b = (bid >> 4) & 15, t = bid >> 8;
    const unsigned long long* mbase = msT + ((size_t)(t * 16 + b) * 1024 + g * 64) * 6;
    unsigned long long m = mbase[tid];           // 384 words: n-local = tid/6, e = tid%6
    unsigned long long anyb = __ballot(m != 0ull);
    if ((tid & 63) == 0) wflag[tid >> 6] = (anyb != 0ull) ? 1u : 0u;
    __syncthreads();
    unsigned int any = wflag[0] | wflag[1] | wflag[2] | wflag[3] | wflag[4] | wflag[5];
    if (!any) return;                            // k2's optimistic write already correct

    // slow path (never taken on this input): per-n VGPR gather.
    // word e: bit j -> input channel j*6 + e   [matches k2's layout]
    size_t obase = (size_t)(t * 16 + b) * 384;
    float pi = pinv_[tid], po = poff_[tid], bb = bp[tid];
    for (int nl = 0; nl < 64; ++nl) {
        float acc = 0.f;
        #pragma unroll
        for (int u = 0; u < 6; ++u) {
            unsigned long long mm = mbase[nl * 6 + u];
            while (mm) {
                int j = __builtin_ctzll(mm);
                mm &= mm - 1;
                int row = j * 6 + u;
                acc += wpT[(size_t)row * 384 + tid];
            }
        }
        out[(obase + tid) * 1024 + g * 64 + nl] = (acc + bb) * pi + po;
    }
}

extern "C" void kernel_launch(void* const* d_in, const int* in_sizes, int n_in,
                              void* d_out, int out_size, void* d_ws, size_t ws_size,
                              hipStream_t stream) {
    const float* x  = (const float*)d_in[0];
    const unsigned char* ak = (const unsigned char*)d_in[1];
    const unsigned char* av = (const unsigned char*)d_in[2];
    const float* wq = (const float*)d_in[3];
    const float* qg = (const float*)d_in[4];
    const float* qb = (const float*)d_in[5];
    const float* qm = (const float*)d_in[6];
    const float* qv = (const float*)d_in[7];
    const float* wp = (const float*)d_in[8];
    const float* bp = (const float*)d_in[9];
    const float* pg = (const float*)d_in[10];
    const float* pb = (const float*)d_in[11];
    const float* pm = (const float*)d_in[12];
    const float* pv = (const float*)d_in[13];
    char* ws = (char*)d_ws;
    float* out = (float*)d_out;

    hipLaunchKernelGGL(k01_lif_prep, dim3(25737), dim3(256), 0, stream,
                       x, wq, wp, qg, qb, qm, qv, pg, pb, pm, pv, bp,
                       (unsigned long long*)(ws + XM_OFF), ws);
    hipLaunchKernelGGL(k1bc, dim3(256), dim3(256), 0, stream,
                       (const unsigned long long*)(ws + XM_OFF),
                       (const float*)(ws + ROWMAX_OFF),
                       (const float*)(ws + MAXQ_OFF),
                       (unsigned long long*)(ws + XMT_OFF),
                       (unsigned short*)(ws + LISTS2_OFF),
                       (unsigned char*)(ws + LCNT2_OFF),
                       (unsigned char*)(ws + ABND_OFF));
    hipLaunchKernelGGL(k2_qpath, dim3(1024), dim3(512), 0, stream,
                       (const char*)(ws + WQB_OFF),
                       (const float*)(ws + QINV_OFF), (const float*)(ws + QOFF_OFF),
                       (const unsigned short*)(ws + LISTS2_OFF),
                       (const unsigned char*)(ws + LCNT2_OFF),
                       (const unsigned char*)(ws + ABND_OFF),
                       (const unsigned long long*)(ws + XMT_OFF), ak, av,
                       (const float*)(ws + C0_OFF),
                       (unsigned long long*)(ws + MST_OFF), out);
    hipLaunchKernelGGL(k3_proj, dim3(1024), dim3(384), 0, stream,
                       (const float*)(ws + WPT_OFF), (const float*)(ws + PINV_OFF),
                       (const float*)(ws + POFF_OFF), bp,
                       (const unsigned long long*)(ws + MST_OFF), out);
}

// Round 20
// 86.814 us; speedup vs baseline: 2.0353x; 1.0527x over previous
//
#include <hip/hip_runtime.h>
#include <cstdint>

#define CN (384*1024)          // 393216
#define BCN (16*CN)            // 6291456
#define EPS 1e-5f

typedef float f32x2 __attribute__((ext_vector_type(2)));
typedef float f32x4 __attribute__((ext_vector_type(4)));

// workspace layout (bytes)
#define WPT_OFF   0u           // f32[384][384] = 589824
#define WQB_OFF   589824u      // bf16-as-u16[385][384] (row 384 = zeros), ends 885504
#define QINV_OFF  1179648u
#define QOFF_OFF  (QINV_OFF + 1536u)
#define PINV_OFF  (QINV_OFF + 3072u)
#define POFF_OFF  (QINV_OFF + 4608u)
#define C0_OFF    (QINV_OFF + 6144u)
#define LCNT2_OFF 1187840u     // u8[1024 blocks][64 units], ends 1253376
#define ROWMAX_OFF 1253376u    // f32[384] max_o |bf16(wq[o,r])|, ends 1254912
#define MAXQ_OFF  1254912u     // f32[2] = {max|qi|, max|qo|}
#define XM_OFF    1310720u     // u64[4][16][16][384] n-packed spikes, ends 4456448
#define XMT_OFF   4456448u     // u64[4][16][1024][6] c-packed spikes, ends 7602176
#define LISTS2_OFF 7602176u    // u16[1024][64][24] offsets (idx*3), ends 10747904
#define ABND_OFF  10747904u    // u8[1024][64] quantized unit bounds A*64 (ceil), ends 10813440
#define MST_OFF   XM_OFF       // masked q-spikes u64[col][6]; reuses xm (dead after k1bc)

// ---------------- K01: fused {LIF -> bitmasks} + {weight prep + consts + rowmax} ---
// blocks [0,1536): LIF, wave = (b,c) pair, 16 g x 4 t = 64 independent 256B loads;
// [1536,2690): wpT/wqb; [2690]: consts+maxq; [2691,2697): rowmax.
__global__ __launch_bounds__(256) void k01_lif_prep(const float* __restrict__ x,
                                                    const float* __restrict__ wq,
                                                    const float* __restrict__ wp,
                                                    const float* __restrict__ qg,
                                                    const float* __restrict__ qb,
                                                    const float* __restrict__ qm,
                                                    const float* __restrict__ qv,
                                                    const float* __restrict__ pg,
                                                    const float* __restrict__ pb,
                                                    const float* __restrict__ pm,
                                                    const float* __restrict__ pv,
                                                    const float* __restrict__ bp,
                                                    unsigned long long* __restrict__ xm,
                                                    char* __restrict__ ws) {
    if (blockIdx.x < 1536) {
        const int wv   = threadIdx.x >> 6;
        const int lane = threadIdx.x & 63;
        const int pid  = blockIdx.x * 4 + wv;           // 0..6143 = b*384 + c
        const int b = pid / 384, c = pid % 384;
        const float* xp = x + (size_t)b * CN + (size_t)c * 1024 + lane;
        float v[16];
        #pragma unroll
        for (int g = 0; g < 16; ++g) v[g] = 0.f;
        #pragma unroll
        for (int t = 0; t < 4; ++t) {
            float xv[16];
            #pragma unroll
            for (int g = 0; g < 16; ++g)                // 16 independent 256B loads
                xv[g] = xp[(size_t)t * BCN + g * 64];
            #pragma unroll
            for (int g = 0; g < 16; ++g) {
                float h = v[g] + (xv[g] - v[g]) * 0.5f; // v + (x - v)/tau, tau = 2
                bool s = (h >= 1.0f);
                unsigned long long m = __ballot(s);
                v[g] = s ? 0.f : h;
                if (lane == 0) xm[(((size_t)t * 16 + b) * 16 + g) * 384 + c] = m;
            }
        }
        return;
    }
    int bid = blockIdx.x - 1536;                     // 0..1160
    if (bid < 576) {
        int i = bid * 256 + threadIdx.x;             // 0..147455
        int c = i / 384, o = i % 384;
        ((float*)(ws + WPT_OFF))[c * 384 + o] = wp[o * 384 + c];
    } else if (bid < 1154) {
        int j = (bid - 576) * 256 + threadIdx.x;     // 0..147967
        if (j >= 147840) return;                     // 385*384
        int r = j / 384, o = j % 384;
        unsigned short v = 0;
        if (r < 384) {
            unsigned u = __float_as_uint(wq[o * 384 + r]);
            v = (unsigned short)((u + 0x7fffu + ((u >> 16) & 1u)) >> 16);  // rne bf16
        }
        ((unsigned short*)(ws + WQB_OFF))[j] = v;
    } else if (bid == 1154) {
        __shared__ float smi[256], smo[256];
        float mi = 0.f, mo = 0.f;
        for (int i = threadIdx.x; i < 384; i += 256) {
            float qi = qg[i] / sqrtf(qv[i] + EPS);
            ((float*)(ws + QINV_OFF))[i] = qi;
            float qov = qb[i] - qm[i] * qi;
            ((float*)(ws + QOFF_OFF))[i] = qov;
            float pi = pg[i] / sqrtf(pv[i] + EPS);
            float po = pb[i] - pm[i] * pi;
            ((float*)(ws + PINV_OFF))[i] = pi;
            ((float*)(ws + POFF_OFF))[i] = po;
            ((float*)(ws + C0_OFF))[i] = bp[i] * pi + po;  // output when GEMM2 input == 0
            mi = fmaxf(mi, fabsf(qi));
            mo = fmaxf(mo, fabsf(qov));
        }
        smi[threadIdx.x] = mi; smo[threadIdx.x] = mo;
        __syncthreads();
        for (int s = 128; s > 0; s >>= 1) {
            if (threadIdx.x < s) {
                smi[threadIdx.x] = fmaxf(smi[threadIdx.x], smi[threadIdx.x + s]);
                smo[threadIdx.x] = fmaxf(smo[threadIdx.x], smo[threadIdx.x + s]);
            }
            __syncthreads();
        }
        if (threadIdx.x == 0) {
            ((float*)(ws + MAXQ_OFF))[0] = smi[0];
            ((float*)(ws + MAXQ_OFF))[1] = smo[0];
        }
    } else {
        // rowmax: 6 blocks x 64 rows; thread = (row-local<<2)|quarter, 96 o's each
        __shared__ float sm[256];
        int rblk = bid - 1155;                       // 0..5
        int row = rblk * 64 + (threadIdx.x >> 2);
        int qd  = threadIdx.x & 3;
        float m = 0.f;
        for (int o = qd * 96; o < qd * 96 + 96; ++o) {
            unsigned u = __float_as_uint(wq[(size_t)o * 384 + row]);
            unsigned bbits = (u + 0x7fffu + ((u >> 16) & 1u)) >> 16;   // rne bf16
            m = fmaxf(m, __uint_as_float((bbits & 0x7fffu) << 16));    // |bf16|
        }
        sm[threadIdx.x] = m;
        __syncthreads();
        if (qd == 0) {
            float r0 = fmaxf(fmaxf(sm[threadIdx.x], sm[threadIdx.x + 1]),
                             fmaxf(sm[threadIdx.x + 2], sm[threadIdx.x + 3]));
            ((float*)(ws + ROWMAX_OFF))[row] = r0;
        }
    }
}

// ---------------- K1bc: fused bit-transpose + offset-list + unit-bound build -------
// wave = (t,b,g). 64 ballots x6 -> lane n holds its column's 6 c-packed words;
// writes xmT, builds padded u16 offset list + lcnt, and the quantized unit bound
// A = maxqi * sum(rowmax[list]) + maxqo (ceil to 1/64 units, sat 255 -> never skip).
__global__ __launch_bounds__(256) void k1bc(const unsigned long long* __restrict__ xm,
                                            const float* __restrict__ rowmaxp,
                                            const float* __restrict__ maxqp,
                                            unsigned long long* __restrict__ xmT,
                                            unsigned short* __restrict__ lists2,
                                            unsigned char* __restrict__ lcnt2,
                                            unsigned char* __restrict__ abnd) {
    int wid  = (blockIdx.x * 256 + threadIdx.x) >> 6;   // 0..1023 = tb*16+g
    int lane = threadIdx.x & 63;
    int g  = wid & 15;
    int tb = wid >> 4;                                  // t*16 + b
    unsigned long long T[6];
    #pragma unroll
    for (int cg = 0; cg < 6; ++cg) {
        unsigned long long W = xm[((size_t)tb * 16 + g) * 384 + cg * 64 + lane];
        unsigned long long colw = 0ull;
        #pragma unroll
        for (int k = 0; k < 64; ++k) {
            unsigned long long bk = __ballot((W >> k) & 1ull);
            if (lane == k) colw = bk;
        }
        T[cg] = colw;
    }
    const int n   = g * 64 + lane;
    const size_t col = ((size_t)tb << 10) + n;
    #pragma unroll
    for (int cg = 0; cg < 6; ++cg) xmT[col * 6 + cg] = T[cg];
    const int blockid = (tb & 15) * 64 + (n >> 4);      // b*64 + n/16
    const int un = (n & 15) * 4 + (tb >> 4);            // (n%16)*4 + t
    unsigned short* lp = lists2 + ((size_t)blockid * 64 + un) * 24;
    int k = 0;
    float S = 0.f;
    #pragma unroll
    for (int cg = 0; cg < 6; ++cg) {
        unsigned long long m = T[cg];
        while (m) {
            int j = __builtin_ctzll(m);
            m &= m - 1;
            S += rowmaxp[cg * 64 + j];
            if (k < 24) lp[k] = (unsigned short)((cg * 64 + j) * 3);
            ++k;
        }
    }
    int kk = k > 24 ? 24 : k;
    for (int i = kk; i < 24; ++i) lp[i] = 1152;         // 384*3 -> zero row (always pad)
    lcnt2[(size_t)blockid * 64 + un] =
        (k > 24) ? 0xFF : (unsigned char)((k + 7) >> 3);
    float A = maxqp[0] * S + maxqp[1];
    int aq = (int)ceilf(A * 64.f);
    abnd[(size_t)blockid * 64 + un] = (unsigned char)(aq > 255 ? 255 : (aq < 0 ? 0 : aq));
}

// ---------------- K2: bound-skip + wave-per-row gather GEMM1 + fused BN/LIF --------
// block = (b, nt16), 512 threads = 8 waves; wave w owns n-locals {2w, 2w+1}.
// Per column: LIF interval recursion on the quantized unit bounds proves ~85% of
// columns spike-free -> write msT=0, skip the gather entirely (tail write is exact).
// Else: dwordx3 row gather (lane owns o=lane*6+e), fused per-t BN/LIF/mask epilogue.
// Tail: unconditional constant write out = c0[o]; spiked tiles rewritten by k3.
#define BLO(w) __uint_as_float((w) << 16)
#define BHI(w) __uint_as_float((w) & 0xFFFF0000u)
#define PK(w)  ((f32x2){BLO(w), BHI(w)})
#define RL(v, l) ((unsigned)__builtin_amdgcn_readlane((int)(v), (l)))

#define GROW8(W0, W1, W2, W3) do {                                                \
    uint3 d0_ = *(const uint3*)(wqc + ((size_t)((W0) & 0xffffu) << 8) + voff);    \
    uint3 d1_ = *(const uint3*)(wqc + ((size_t)((W0) >> 16) << 8) + voff);        \
    uint3 d2_ = *(const uint3*)(wqc + ((size_t)((W1) & 0xffffu) << 8) + voff);    \
    uint3 d3_ = *(const uint3*)(wqc + ((size_t)((W1) >> 16) << 8) + voff);        \
    uint3 d4_ = *(const uint3*)(wqc + ((size_t)((W2) & 0xffffu) << 8) + voff);    \
    uint3 d5_ = *(const uint3*)(wqc + ((size_t)((W2) >> 16) << 8) + voff);        \
    uint3 d6_ = *(const uint3*)(wqc + ((size_t)((W3) & 0xffffu) << 8) + voff);    \
    uint3 d7_ = *(const uint3*)(wqc + ((size_t)((W3) >> 16) << 8) + voff);        \
    s0 += ((PK(d0_.x) + PK(d1_.x)) + (PK(d2_.x) + PK(d3_.x)))                     \
        + ((PK(d4_.x) + PK(d5_.x)) + (PK(d6_.x) + PK(d7_.x)));                    \
    s1 += ((PK(d0_.y) + PK(d1_.y)) + (PK(d2_.y) + PK(d3_.y)))                     \
        + ((PK(d4_.y) + PK(d5_.y)) + (PK(d6_.y) + PK(d7_.y)));                    \
    s2 += ((PK(d0_.z) + PK(d1_.z)) + (PK(d2_.z) + PK(d3_.z)))                     \
        + ((PK(d4_.z) + PK(d5_.z)) + (PK(d6_.z) + PK(d7_.z)));                    \
} while (0)

__global__ __launch_bounds__(512) void k2_qpath(const char* __restrict__ wqc,
                                                const float* __restrict__ qinv_,
                                                const float* __restrict__ qoff_,
                                                const unsigned short* __restrict__ lists2,
                                                const unsigned char* __restrict__ lcnt2,
                                                const unsigned char* __restrict__ abnd,
                                                const unsigned long long* __restrict__ xmT,
                                                const unsigned char* __restrict__ ak,
                                                const unsigned char* __restrict__ av,
                                                const float* __restrict__ c0,
                                                unsigned long long* __restrict__ msT,
                                                float* __restrict__ out) {
    const int tid  = threadIdx.x;
    const int lane = tid & 63;
    const int w    = tid >> 6;                   // wave 0..7
    const int nt   = blockIdx.x & 63;
    const int b    = blockIdx.x >> 6;
    const int voff = lane * 12;                  // 12B per lane: o = lane*6 + e

    // lane-cache the block's gather metadata: lane u holds unit u's 24 u16 offsets
    const char* lb = (const char*)lists2 + (size_t)blockIdx.x * 3072 + lane * 48;
    const uint4 L0 = *(const uint4*)lb;           // slots 0-7
    const uint4 L1 = *(const uint4*)(lb + 16);    // slots 8-15
    const uint4 L2 = *(const uint4*)(lb + 32);    // slots 16-23
    const unsigned lcv = *(const unsigned*)((const char*)lcnt2
                          + (size_t)blockIdx.x * 64 + (lane & 15) * 4);
    const unsigned abv = *(const unsigned*)((const char*)abnd
                          + (size_t)blockIdx.x * 64 + (lane & 15) * 4);

    float qi[6], qo[6];
    #pragma unroll
    for (int e = 0; e < 6; ++e) {
        qi[e] = qinv_[lane * 6 + e];
        qo[e] = qoff_[lane * 6 + e];
    }

    #pragma unroll
    for (int i = 0; i < 2; ++i) {
        const int nl = w * 2 + i;                // n-local 0..15 (wave-uniform)
        const int n  = nt * 16 + nl;
        const unsigned abw = RL(abv, nl);        // 4 quantized unit bounds
        // ---- LIF interval recursion on bounds: prove no spike at any t ----
        float hb = 0.f;
        bool skip = true;
        #pragma unroll
        for (int t = 0; t < 4; ++t) {
            float A = (float)((abw >> (8 * t)) & 0xffu) * 0.015625f + 0.015625f;
            hb = 0.5f * (hb + A);
            skip = skip && (hb < 1.0f);
        }
        if (skip) {                               // provably spike-free column
            if (lane < 6) {
                #pragma unroll
                for (int t = 0; t < 4; ++t)
                    msT[(size_t)(((t * 16 + b) << 10) + n) * 6 + lane] = 0ull;
            }
            continue;
        }
        const unsigned lcw = RL(lcv, nl);        // 4 round-counts (one per t)
        float v[6] = {0.f, 0.f, 0.f, 0.f, 0.f, 0.f};
        #pragma unroll
        for (int t = 0; t < 4; ++t) {
            const int un = nl * 4 + t;           // wave-uniform unit index
            const unsigned r_ = (lcw >> (8 * t)) & 0xffu;
            f32x2 s0 = {0.f, 0.f}, s1 = {0.f, 0.f}, s2 = {0.f, 0.f};
            // ---- 16 unconditional slots (padded; zero row absorbs empties) ----
            {
                const unsigned Wa = RL(L0.x, un), Wb = RL(L0.y, un);
                const unsigned Wc = RL(L0.z, un), Wd = RL(L0.w, un);
                const unsigned We = RL(L1.x, un), Wf = RL(L1.y, un);
                const unsigned Wg = RL(L1.z, un), Wh = RL(L1.w, un);
                GROW8(Wa, Wb, Wc, Wd);
                GROW8(We, Wf, Wg, Wh);
            }
            // ---- rare third round (k = 17..24) ----
            if (r_ == 3u) {
                const unsigned Wa = RL(L2.x, un), Wb = RL(L2.y, un);
                const unsigned Wc = RL(L2.z, un), Wd = RL(L2.w, un);
                GROW8(Wa, Wb, Wc, Wd);
            }
            // ---- overflow fallback (k > 24, ~never): recompute from zero ----
            if (r_ == 0xffu) {
                const int colf = ((t * 16 + b) << 10) + n;
                const unsigned long long* mp = xmT + (size_t)colf * 6;
                s0 = (f32x2){0.f, 0.f}; s1 = (f32x2){0.f, 0.f}; s2 = (f32x2){0.f, 0.f};
                #pragma unroll
                for (int cg = 0; cg < 6; ++cg) {
                    unsigned long long mm = mp[cg];
                    while (mm) {
                        int j = __builtin_ctzll(mm);
                        mm &= mm - 1;
                        uint3 dd = *(const uint3*)(wqc + (size_t)(cg * 64 + j) * 768 + voff);
                        s0 += PK(dd.x); s1 += PK(dd.y); s2 += PK(dd.z);
                    }
                }
            }
            // ---- fused BN + LIF + attn-mask epilogue for this t ----
            const int col = ((t * 16 + b) << 10) + n;
            const float val[6] = {s0.x, s0.y, s1.x, s1.y, s2.x, s2.y};
            bool sp[6];
            #pragma unroll
            for (int e = 0; e < 6; ++e) {
                float q = val[e] * qi[e] + qo[e];
                float h = 0.5f * (v[e] + q);     // v + (q - v)/2
                bool s = (h >= 1.0f);
                v[e] = s ? 0.f : h;
                if (s) {                          // rare: attn lookup only on q-spike
                    size_t ix = ((size_t)((t * 16 + b) * 384 + lane * 6 + e) << 10) + n;
                    s = (ak[ix] != 0) && (av[ix] != 0);
                }
                sp[e] = s;
            }
            unsigned long long B0 = __ballot(sp[0]);
            unsigned long long B1 = __ballot(sp[1]);
            unsigned long long B2 = __ballot(sp[2]);
            unsigned long long B3 = __ballot(sp[3]);
            unsigned long long B4 = __ballot(sp[4]);
            unsigned long long B5 = __ballot(sp[5]);
            // word e: bit l -> o = l*6 + e
            unsigned long long sel = lane == 0 ? B0 : lane == 1 ? B1 : lane == 2 ? B2
                                   : lane == 3 ? B3 : lane == 4 ? B4 : B5;
            if (lane < 6) msT[(size_t)col * 6 + lane] = sel;
        }
    }

    // ---- tail optimistic constant write (issues after ALL loads; drains async) ----
    // tile = 384 o x 16 n floats = 1536 float4 units = 3 x 512 threads, 64B chunks.
    {
        float cv[3];
        #pragma unroll
        for (int k = 0; k < 3; ++k) cv[k] = c0[(tid + k * 512) >> 2];
        #pragma unroll
        for (int t = 0; t < 4; ++t) {
            f32x4* base4 = (f32x4*)out + (size_t)(t * 16 + b) * 384 * 256 + nt * 4;
            #pragma unroll
            for (int k = 0; k < 3; ++k) {
                int i2 = tid + k * 512;                 // 0..1535
                int o = i2 >> 2, n4 = i2 & 3;           // o in [0,384), n4 in [0,4)
                float vv = cv[k];
                __builtin_nontemporal_store((f32x4){vv, vv, vv, vv},
                                            base4 + (size_t)o * 256 + n4);
            }
        }
    }
}

// ---------------- K3: slow-path guard (gather GEMM2 only where spikes exist) -------
__global__ __launch_bounds__(384) void k3_proj(const float* __restrict__ wpT,
                                               const float* __restrict__ pinv_,
                                               const float* __restrict__ poff_,
                                               const float* __restrict__ bp,
                                               const unsigned long long* __restrict__ msT,
                                               float* __restrict__ out) {
    __shared__ unsigned int wflag[6];
    const int tid = threadIdx.x;
    const int bid = blockIdx.x;
    const int g = bid & 15, b = (bid >> 4) & 15, t = bid >> 8;
    const unsigned long long* mbase = msT + ((size_t)(t * 16 + b) * 1024 + g * 64) * 6;
    unsigned long long m = mbase[tid];           // 384 words: n-local = tid/6, e = tid%6
    unsigned long long anyb = __ballot(m != 0ull);
    if ((tid & 63) == 0) wflag[tid >> 6] = (anyb != 0ull) ? 1u : 0u;
    __syncthreads();
    unsigned int any = wflag[0] | wflag[1] | wflag[2] | wflag[3] | wflag[4] | wflag[5];
    if (!any) return;                            // k2's optimistic write already correct

    // slow path (never taken on this input): per-n VGPR gather.
    // word e: bit j -> input channel j*6 + e   [matches k2's layout]
    size_t obase = (size_t)(t * 16 + b) * 384;
    float pi = pinv_[tid], po = poff_[tid], bb = bp[tid];
    for (int nl = 0; nl < 64; ++nl) {
        float acc = 0.f;
        #pragma unroll
        for (int u = 0; u < 6; ++u) {
            unsigned long long mm = mbase[nl * 6 + u];
            while (mm) {
                int j = __builtin_ctzll(mm);
                mm &= mm - 1;
                int row = j * 6 + u;
                acc += wpT[(size_t)row * 384 + tid];
            }
        }
        out[(obase + tid) * 1024 + g * 64 + nl] = (acc + bb) * pi + po;
    }
}

extern "C" void kernel_launch(void* const* d_in, const int* in_sizes, int n_in,
                              void* d_out, int out_size, void* d_ws, size_t ws_size,
                              hipStream_t stream) {
    const float* x  = (const float*)d_in[0];
    const unsigned char* ak = (const unsigned char*)d_in[1];
    const unsigned char* av = (const unsigned char*)d_in[2];
    const float* wq = (const float*)d_in[3];
    const float* qg = (const float*)d_in[4];
    const float* qb = (const float*)d_in[5];
    const float* qm = (const float*)d_in[6];
    const float* qv = (const float*)d_in[7];
    const float* wp = (const float*)d_in[8];
    const float* bp = (const float*)d_in[9];
    const float* pg = (const float*)d_in[10];
    const float* pb = (const float*)d_in[11];
    const float* pm = (const float*)d_in[12];
    const float* pv = (const float*)d_in[13];
    char* ws = (char*)d_ws;
    float* out = (float*)d_out;

    hipLaunchKernelGGL(k01_lif_prep, dim3(2697), dim3(256), 0, stream,
                       x, wq, wp, qg, qb, qm, qv, pg, pb, pm, pv, bp,
                       (unsigned long long*)(ws + XM_OFF), ws);
    hipLaunchKernelGGL(k1bc, dim3(256), dim3(256), 0, stream,
                       (const unsigned long long*)(ws + XM_OFF),
                       (const float*)(ws + ROWMAX_OFF),
                       (const float*)(ws + MAXQ_OFF),
                       (unsigned long long*)(ws + XMT_OFF),
                       (unsigned short*)(ws + LISTS2_OFF),
                       (unsigned char*)(ws + LCNT2_OFF),
                       (unsigned char*)(ws + ABND_OFF));
    hipLaunchKernelGGL(k2_qpath, dim3(1024), dim3(512), 0, stream,
                       (const char*)(ws + WQB_OFF),
                       (const float*)(ws + QINV_OFF), (const float*)(ws + QOFF_OFF),
                       (const unsigned short*)(ws + LISTS2_OFF),
                       (const unsigned char*)(ws + LCNT2_OFF),
                       (const unsigned char*)(ws + ABND_OFF),
                       (const unsigned long long*)(ws + XMT_OFF), ak, av,
                       (const float*)(ws + C0_OFF),
                       (unsigned long long*)(ws + MST_OFF), out);
    hipLaunchKernelGGL(k3_proj, dim3(1024), dim3(384), 0, stream,
                       (const float*)(ws + WPT_OFF), (const float*)(ws + PINV_OFF),
                       (const float*)(ws + POFF_OFF), bp,
                       (const unsigned long long*)(ws + MST_OFF), out);
}

// Round 21
// 86.406 us; speedup vs baseline: 2.0449x; 1.0047x over previous
//
#include <hip/hip_runtime.h>
#include <cstdint>

#define CN (384*1024)          // 393216
#define BCN (16*CN)            // 6291456
#define EPS 1e-5f

typedef float f32x2 __attribute__((ext_vector_type(2)));
typedef float f32x4 __attribute__((ext_vector_type(4)));

// workspace layout (bytes)
#define WPT_OFF   0u           // f32[384][384] = 589824
#define WQB_OFF   589824u      // bf16-as-u16[385][384] (row 384 = zeros), ends 885504
#define QINV_OFF  1179648u
#define QOFF_OFF  (QINV_OFF + 1536u)
#define PINV_OFF  (QINV_OFF + 3072u)
#define POFF_OFF  (QINV_OFF + 4608u)
#define LCNT2_OFF 1187840u     // u8[1024 blocks][64 units], ends 1253376
#define ROWMAX_OFF 1253376u    // f32[384] max_o |bf16(wq[o,r])|, ends 1254912
#define MAXQ_OFF  1254912u     // f32[2] = {max|qi|, max|qo|}
#define XM_OFF    1310720u     // u64[4][16][16][384] n-packed spikes, ends 4456448
#define XMT_OFF   4456448u     // u64[4][16][1024][6] c-packed spikes, ends 7602176
#define LISTS2_OFF 7602176u    // u16[1024][64][24] offsets (idx*3), ends 10747904
#define ABND_OFF  10747904u    // u8[1024][64] quantized unit bounds A*64 (ceil), ends 10813440
#define MST_OFF   XM_OFF       // masked q-spikes u64[col][6]; reuses xm (dead after k1bc)

// ---------------- K01: {LIF} + {optimistic OUTPUT WRITE} + {prep, all coalesced} ---
// [0,1536): LIF (wave = (b,c), 16g x 4t deep loads)
// [1536,3072): output constant write (block = 16 o-rows; overlaps the x read)
// [3072,3648): wpT transpose (read coalesced, write scattered)
// [3648,4224): wqb bf16 transpose (read coalesced, write scattered)
// [4224]: consts + maxq + wqb zero row
// [4225,4231): rowmax (read coalesced, cross-wave LDS reduce)
__global__ __launch_bounds__(256) void k01_lif_prep(const float* __restrict__ x,
                                                    const float* __restrict__ wq,
                                                    const float* __restrict__ wp,
                                                    const float* __restrict__ qg,
                                                    const float* __restrict__ qb,
                                                    const float* __restrict__ qm,
                                                    const float* __restrict__ qv,
                                                    const float* __restrict__ pg,
                                                    const float* __restrict__ pb,
                                                    const float* __restrict__ pm,
                                                    const float* __restrict__ pv,
                                                    const float* __restrict__ bp,
                                                    unsigned long long* __restrict__ xm,
                                                    char* __restrict__ ws,
                                                    float* __restrict__ out) {
    if (blockIdx.x < 1536) {
        const int wv   = threadIdx.x >> 6;
        const int lane = threadIdx.x & 63;
        const int pid  = blockIdx.x * 4 + wv;           // 0..6143 = b*384 + c
        const int b = pid / 384, c = pid % 384;
        const float* xp = x + (size_t)b * CN + (size_t)c * 1024 + lane;
        float v[16];
        #pragma unroll
        for (int g = 0; g < 16; ++g) v[g] = 0.f;
        #pragma unroll
        for (int t = 0; t < 4; ++t) {
            float xv[16];
            #pragma unroll
            for (int g = 0; g < 16; ++g)                // 16 independent 256B loads
                xv[g] = xp[(size_t)t * BCN + g * 64];
            #pragma unroll
            for (int g = 0; g < 16; ++g) {
                float h = v[g] + (xv[g] - v[g]) * 0.5f; // v + (x - v)/tau, tau = 2
                bool s = (h >= 1.0f);
                unsigned long long m = __ballot(s);
                v[g] = s ? 0.f : h;
                if (lane == 0) xm[(((size_t)t * 16 + b) * 16 + g) * 384 + c] = m;
            }
        }
        return;
    }
    if (blockIdx.x < 3072) {
        // optimistic constant output write: rows [w2*16, w2*16+16) of out[t][b][o][n]
        __shared__ float sc0[16];
        const int w2 = blockIdx.x - 1536;               // 0..1535
        if (threadIdx.x < 16) {
            int o = (w2 * 16 + threadIdx.x) % 384;
            float pi = pg[o] / sqrtf(pv[o] + EPS);
            float po = pb[o] - pm[o] * pi;
            sc0[threadIdx.x] = bp[o] * pi + po;         // value when GEMM2 input == 0
        }
        __syncthreads();
        f32x4* ob = (f32x4*)out + (size_t)w2 * 4096;
        #pragma unroll
        for (int k = 0; k < 16; ++k) {
            float vv = sc0[k];
            __builtin_nontemporal_store((f32x4){vv, vv, vv, vv},
                                        ob + k * 256 + threadIdx.x);
        }
        return;
    }
    if (blockIdx.x < 3648) {
        int i = (blockIdx.x - 3072) * 256 + threadIdx.x;   // 0..147455
        int o = i / 384, c = i % 384;                      // read coalesced over c
        ((float*)(ws + WPT_OFF))[c * 384 + o] = wp[o * 384 + c];
        return;
    }
    if (blockIdx.x < 4224) {
        int j = (blockIdx.x - 3648) * 256 + threadIdx.x;   // 0..147455
        int o = j / 384, r = j % 384;                      // read coalesced over r
        unsigned u = __float_as_uint(wq[o * 384 + r]);
        unsigned short v = (unsigned short)((u + 0x7fffu + ((u >> 16) & 1u)) >> 16);
        ((unsigned short*)(ws + WQB_OFF))[r * 384 + o] = v;  // rne bf16, scattered store
        return;
    }
    if (blockIdx.x == 4224) {
        __shared__ float smi[256], smo[256];
        float mi = 0.f, mo = 0.f;
        for (int i = threadIdx.x; i < 384; i += 256) {
            float qi = qg[i] / sqrtf(qv[i] + EPS);
            ((float*)(ws + QINV_OFF))[i] = qi;
            float qov = qb[i] - qm[i] * qi;
            ((float*)(ws + QOFF_OFF))[i] = qov;
            float pi = pg[i] / sqrtf(pv[i] + EPS);
            ((float*)(ws + PINV_OFF))[i] = pi;
            ((float*)(ws + POFF_OFF))[i] = pb[i] - pm[i] * pi;
            ((unsigned short*)(ws + WQB_OFF))[384 * 384 + i] = 0;   // zero row 384
            mi = fmaxf(mi, fabsf(qi));
            mo = fmaxf(mo, fabsf(qov));
        }
        smi[threadIdx.x] = mi; smo[threadIdx.x] = mo;
        __syncthreads();
        for (int s = 128; s > 0; s >>= 1) {
            if (threadIdx.x < s) {
                smi[threadIdx.x] = fmaxf(smi[threadIdx.x], smi[threadIdx.x + s]);
                smo[threadIdx.x] = fmaxf(smo[threadIdx.x], smo[threadIdx.x + s]);
            }
            __syncthreads();
        }
        if (threadIdx.x == 0) {
            ((float*)(ws + MAXQ_OFF))[0] = smi[0];
            ((float*)(ws + MAXQ_OFF))[1] = smo[0];
        }
        return;
    }
    {
        // rowmax: 6 blocks; block covers r in [rb*64, rb*64+64); coalesced reads
        __shared__ float sm2[4][64];
        const int rb = blockIdx.x - 4225;               // 0..5
        const int lane = threadIdx.x & 63;
        const int wv = threadIdx.x >> 6;                // 0..3, 96 o's each
        const int r = rb * 64 + lane;
        float m = 0.f;
        for (int o = wv * 96; o < wv * 96 + 96; ++o) {
            unsigned u = __float_as_uint(wq[(size_t)o * 384 + r]);
            unsigned bbits = (u + 0x7fffu + ((u >> 16) & 1u)) >> 16;   // rne bf16
            m = fmaxf(m, __uint_as_float((bbits & 0x7fffu) << 16));    // |bf16|
        }
        sm2[wv][lane] = m;
        __syncthreads();
        if (wv == 0) {
            float r0 = fmaxf(fmaxf(sm2[0][lane], sm2[1][lane]),
                             fmaxf(sm2[2][lane], sm2[3][lane]));
            ((float*)(ws + ROWMAX_OFF))[r] = r0;
        }
    }
}

// ---------------- K1bc: fused bit-transpose + offset-list + unit-bound build -------
__global__ __launch_bounds__(256) void k1bc(const unsigned long long* __restrict__ xm,
                                            const float* __restrict__ rowmaxp,
                                            const float* __restrict__ maxqp,
                                            unsigned long long* __restrict__ xmT,
                                            unsigned short* __restrict__ lists2,
                                            unsigned char* __restrict__ lcnt2,
                                            unsigned char* __restrict__ abnd) {
    int wid  = (blockIdx.x * 256 + threadIdx.x) >> 6;   // 0..1023 = tb*16+g
    int lane = threadIdx.x & 63;
    int g  = wid & 15;
    int tb = wid >> 4;                                  // t*16 + b
    unsigned long long T[6];
    #pragma unroll
    for (int cg = 0; cg < 6; ++cg) {
        unsigned long long W = xm[((size_t)tb * 16 + g) * 384 + cg * 64 + lane];
        unsigned long long colw = 0ull;
        #pragma unroll
        for (int k = 0; k < 64; ++k) {
            unsigned long long bk = __ballot((W >> k) & 1ull);
            if (lane == k) colw = bk;
        }
        T[cg] = colw;
    }
    const int n   = g * 64 + lane;
    const size_t col = ((size_t)tb << 10) + n;
    #pragma unroll
    for (int cg = 0; cg < 6; ++cg) xmT[col * 6 + cg] = T[cg];
    const int blockid = (tb & 15) * 64 + (n >> 4);      // b*64 + n/16
    const int un = (n & 15) * 4 + (tb >> 4);            // (n%16)*4 + t
    unsigned short* lp = lists2 + ((size_t)blockid * 64 + un) * 24;
    int k = 0;
    float S = 0.f;
    #pragma unroll
    for (int cg = 0; cg < 6; ++cg) {
        unsigned long long m = T[cg];
        while (m) {
            int j = __builtin_ctzll(m);
            m &= m - 1;
            S += rowmaxp[cg * 64 + j];
            if (k < 24) lp[k] = (unsigned short)((cg * 64 + j) * 3);
            ++k;
        }
    }
    int kk = k > 24 ? 24 : k;
    for (int i = kk; i < 24; ++i) lp[i] = 1152;         // 384*3 -> zero row (always pad)
    lcnt2[(size_t)blockid * 64 + un] =
        (k > 24) ? 0xFF : (unsigned char)((k + 7) >> 3);
    float A = maxqp[0] * S + maxqp[1];
    int aq = (int)ceilf(A * 64.f);
    abnd[(size_t)blockid * 64 + un] = (unsigned char)(aq > 255 ? 255 : (aq < 0 ? 0 : aq));
}

// ---------------- K2: bound-skip + wave-per-row gather GEMM1 + fused BN/LIF --------
// block = (b, nt16), 512 threads = 8 waves; wave w owns n-locals {2w, 2w+1}.
// LIF interval recursion on the quantized bounds proves most columns spike-free ->
// msT=0, no gather (k01's constant write is already exact there). Else: dwordx3
// row gather + fused per-t BN/LIF/mask epilogue. NO output writes here anymore.
#define BLO(w) __uint_as_float((w) << 16)
#define BHI(w) __uint_as_float((w) & 0xFFFF0000u)
#define PK(w)  ((f32x2){BLO(w), BHI(w)})
#define RL(v, l) ((unsigned)__builtin_amdgcn_readlane((int)(v), (l)))

#define GROW8(W0, W1, W2, W3) do {                                                \
    uint3 d0_ = *(const uint3*)(wqc + ((size_t)((W0) & 0xffffu) << 8) + voff);    \
    uint3 d1_ = *(const uint3*)(wqc + ((size_t)((W0) >> 16) << 8) + voff);        \
    uint3 d2_ = *(const uint3*)(wqc + ((size_t)((W1) & 0xffffu) << 8) + voff);    \
    uint3 d3_ = *(const uint3*)(wqc + ((size_t)((W1) >> 16) << 8) + voff);        \
    uint3 d4_ = *(const uint3*)(wqc + ((size_t)((W2) & 0xffffu) << 8) + voff);    \
    uint3 d5_ = *(const uint3*)(wqc + ((size_t)((W2) >> 16) << 8) + voff);        \
    uint3 d6_ = *(const uint3*)(wqc + ((size_t)((W3) & 0xffffu) << 8) + voff);    \
    uint3 d7_ = *(const uint3*)(wqc + ((size_t)((W3) >> 16) << 8) + voff);        \
    s0 += ((PK(d0_.x) + PK(d1_.x)) + (PK(d2_.x) + PK(d3_.x)))                     \
        + ((PK(d4_.x) + PK(d5_.x)) + (PK(d6_.x) + PK(d7_.x)));                    \
    s1 += ((PK(d0_.y) + PK(d1_.y)) + (PK(d2_.y) + PK(d3_.y)))                     \
        + ((PK(d4_.y) + PK(d5_.y)) + (PK(d6_.y) + PK(d7_.y)));                    \
    s2 += ((PK(d0_.z) + PK(d1_.z)) + (PK(d2_.z) + PK(d3_.z)))                     \
        + ((PK(d4_.z) + PK(d5_.z)) + (PK(d6_.z) + PK(d7_.z)));                    \
} while (0)

__global__ __launch_bounds__(512) void k2_qpath(const char* __restrict__ wqc,
                                                const float* __restrict__ qinv_,
                                                const float* __restrict__ qoff_,
                                                const unsigned short* __restrict__ lists2,
                                                const unsigned char* __restrict__ lcnt2,
                                                const unsigned char* __restrict__ abnd,
                                                const unsigned long long* __restrict__ xmT,
                                                const unsigned char* __restrict__ ak,
                                                const unsigned char* __restrict__ av,
                                                unsigned long long* __restrict__ msT) {
    const int tid  = threadIdx.x;
    const int lane = tid & 63;
    const int w    = tid >> 6;                   // wave 0..7
    const int nt   = blockIdx.x & 63;
    const int b    = blockIdx.x >> 6;
    const int voff = lane * 12;                  // 12B per lane: o = lane*6 + e

    // lane-cache the block's gather metadata: lane u holds unit u's 24 u16 offsets
    const char* lb = (const char*)lists2 + (size_t)blockIdx.x * 3072 + lane * 48;
    const uint4 L0 = *(const uint4*)lb;           // slots 0-7
    const uint4 L1 = *(const uint4*)(lb + 16);    // slots 8-15
    const uint4 L2 = *(const uint4*)(lb + 32);    // slots 16-23
    const unsigned lcv = *(const unsigned*)((const char*)lcnt2
                          + (size_t)blockIdx.x * 64 + (lane & 15) * 4);
    const unsigned abv = *(const unsigned*)((const char*)abnd
                          + (size_t)blockIdx.x * 64 + (lane & 15) * 4);

    float qi[6], qo[6];
    #pragma unroll
    for (int e = 0; e < 6; ++e) {
        qi[e] = qinv_[lane * 6 + e];
        qo[e] = qoff_[lane * 6 + e];
    }

    #pragma unroll
    for (int i = 0; i < 2; ++i) {
        const int nl = w * 2 + i;                // n-local 0..15 (wave-uniform)
        const int n  = nt * 16 + nl;
        const unsigned abw = RL(abv, nl);        // 4 quantized unit bounds
        // ---- LIF interval recursion on bounds: prove no spike at any t ----
        float hb = 0.f;
        bool skip = true;
        #pragma unroll
        for (int t = 0; t < 4; ++t) {
            float A = (float)((abw >> (8 * t)) & 0xffu) * 0.015625f + 0.015625f;
            hb = 0.5f * (hb + A);
            skip = skip && (hb < 1.0f);
        }
        if (skip) {                               // provably spike-free column
            if (lane < 6) {
                #pragma unroll
                for (int t = 0; t < 4; ++t)
                    msT[(size_t)(((t * 16 + b) << 10) + n) * 6 + lane] = 0ull;
            }
            continue;
        }
        const unsigned lcw = RL(lcv, nl);        // 4 round-counts (one per t)
        float v[6] = {0.f, 0.f, 0.f, 0.f, 0.f, 0.f};
        #pragma unroll
        for (int t = 0; t < 4; ++t) {
            const int un = nl * 4 + t;           // wave-uniform unit index
            const unsigned r_ = (lcw >> (8 * t)) & 0xffu;
            f32x2 s0 = {0.f, 0.f}, s1 = {0.f, 0.f}, s2 = {0.f, 0.f};
            // ---- 16 unconditional slots (padded; zero row absorbs empties) ----
            {
                const unsigned Wa = RL(L0.x, un), Wb = RL(L0.y, un);
                const unsigned Wc = RL(L0.z, un), Wd = RL(L0.w, un);
                const unsigned We = RL(L1.x, un), Wf = RL(L1.y, un);
                const unsigned Wg = RL(L1.z, un), Wh = RL(L1.w, un);
                GROW8(Wa, Wb, Wc, Wd);
                GROW8(We, Wf, Wg, Wh);
            }
            // ---- rare third round (k = 17..24) ----
            if (r_ == 3u) {
                const unsigned Wa = RL(L2.x, un), Wb = RL(L2.y, un);
                const unsigned Wc = RL(L2.z, un), Wd = RL(L2.w, un);
                GROW8(Wa, Wb, Wc, Wd);
            }
            // ---- overflow fallback (k > 24, ~never): recompute from zero ----
            if (r_ == 0xffu) {
                const int colf = ((t * 16 + b) << 10) + n;
                const unsigned long long* mp = xmT + (size_t)colf * 6;
                s0 = (f32x2){0.f, 0.f}; s1 = (f32x2){0.f, 0.f}; s2 = (f32x2){0.f, 0.f};
                #pragma unroll
                for (int cg = 0; cg < 6; ++cg) {
                    unsigned long long mm = mp[cg];
                    while (mm) {
                        int j = __builtin_ctzll(mm);
                        mm &= mm - 1;
                        uint3 dd = *(const uint3*)(wqc + (size_t)(cg * 64 + j) * 768 + voff);
                        s0 += PK(dd.x); s1 += PK(dd.y); s2 += PK(dd.z);
                    }
                }
            }
            // ---- fused BN + LIF + attn-mask epilogue for this t ----
            const int col = ((t * 16 + b) << 10) + n;
            const float val[6] = {s0.x, s0.y, s1.x, s1.y, s2.x, s2.y};
            bool sp[6];
            #pragma unroll
            for (int e = 0; e < 6; ++e) {
                float q = val[e] * qi[e] + qo[e];
                float h = 0.5f * (v[e] + q);     // v + (q - v)/2
                bool s = (h >= 1.0f);
                v[e] = s ? 0.f : h;
                if (s) {                          // rare: attn lookup only on q-spike
                    size_t ix = ((size_t)((t * 16 + b) * 384 + lane * 6 + e) << 10) + n;
                    s = (ak[ix] != 0) && (av[ix] != 0);
                }
                sp[e] = s;
            }
            unsigned long long B0 = __ballot(sp[0]);
            unsigned long long B1 = __ballot(sp[1]);
            unsigned long long B2 = __ballot(sp[2]);
            unsigned long long B3 = __ballot(sp[3]);
            unsigned long long B4 = __ballot(sp[4]);
            unsigned long long B5 = __ballot(sp[5]);
            // word e: bit l -> o = l*6 + e
            unsigned long long sel = lane == 0 ? B0 : lane == 1 ? B1 : lane == 2 ? B2
                                   : lane == 3 ? B3 : lane == 4 ? B4 : B5;
            if (lane < 6) msT[(size_t)col * 6 + lane] = sel;
        }
    }
}

// ---------------- K3: slow-path guard (gather GEMM2 only where spikes exist) -------
__global__ __launch_bounds__(384) void k3_proj(const float* __restrict__ wpT,
                                               const float* __restrict__ pinv_,
                                               const float* __restrict__ poff_,
                                               const float* __restrict__ bp,
                                               const unsigned long long* __restrict__ msT,
                                               float* __restrict__ out) {
    __shared__ unsigned int wflag[6];
    const int tid = threadIdx.x;
    const int bid = blockIdx.x;
    const int g = bid & 15, b = (bid >> 4) & 15, t = bid >> 8;
    const unsigned long long* mbase = msT + ((size_t)(t * 16 + b) * 1024 + g * 64) * 6;
    unsigned long long m = mbase[tid];           // 384 words: n-local = tid/6, e = tid%6
    unsigned long long anyb = __ballot(m != 0ull);
    if ((tid & 63) == 0) wflag[tid >> 6] = (anyb != 0ull) ? 1u : 0u;
    __syncthreads();
    unsigned int any = wflag[0] | wflag[1] | wflag[2] | wflag[3] | wflag[4] | wflag[5];
    if (!any) return;                            // k01's optimistic write already correct

    // slow path (never taken on this input): per-n VGPR gather.
    // word e: bit j -> input channel j*6 + e   [matches k2's layout]
    size_t obase = (size_t)(t * 16 + b) * 384;
    float pi = pinv_[tid], po = poff_[tid], bb = bp[tid];
    for (int nl = 0; nl < 64; ++nl) {
        float acc = 0.f;
        #pragma unroll
        for (int u = 0; u < 6; ++u) {
            unsigned long long mm = mbase[nl * 6 + u];
            while (mm) {
                int j = __builtin_ctzll(mm);
                mm &= mm - 1;
                int row = j * 6 + u;
                acc += wpT[(size_t)row * 384 + tid];
            }
        }
        out[(obase + tid) * 1024 + g * 64 + nl] = (acc + bb) * pi + po;
    }
}

extern "C" void kernel_launch(void* const* d_in, const int* in_sizes, int n_in,
                              void* d_out, int out_size, void* d_ws, size_t ws_size,
                              hipStream_t stream) {
    const float* x  = (const float*)d_in[0];
    const unsigned char* ak = (const unsigned char*)d_in[1];
    const unsigned char* av = (const unsigned char*)d_in[2];
    const float* wq = (const float*)d_in[3];
    const float* qg = (const float*)d_in[4];
    const float* qb = (const float*)d_in[5];
    const float* qm = (const float*)d_in[6];
    const float* qv = (const float*)d_in[7];
    const float* wp = (const float*)d_in[8];
    const float* bp = (const float*)d_in[9];
    const float* pg = (const float*)d_in[10];
    const float* pb = (const float*)d_in[11];
    const float* pm = (const float*)d_in[12];
    const float* pv = (const float*)d_in[13];
    char* ws = (char*)d_ws;
    float* out = (float*)d_out;

    hipLaunchKernelGGL(k01_lif_prep, dim3(4231), dim3(256), 0, stream,
                       x, wq, wp, qg, qb, qm, qv, pg, pb, pm, pv, bp,
                       (unsigned long long*)(ws + XM_OFF), ws, out);
    hipLaunchKernelGGL(k1bc, dim3(256), dim3(256), 0, stream,
                       (const unsigned long long*)(ws + XM_OFF),
                       (const float*)(ws + ROWMAX_OFF),
                       (const float*)(ws + MAXQ_OFF),
                       (unsigned long long*)(ws + XMT_OFF),
                       (unsigned short*)(ws + LISTS2_OFF),
                       (unsigned char*)(ws + LCNT2_OFF),
                       (unsigned char*)(ws + ABND_OFF));
    hipLaunchKernelGGL(k2_qpath, dim3(1024), dim3(512), 0, stream,
                       (const char*)(ws + WQB_OFF),
                       (const float*)(ws + QINV_OFF), (const float*)(ws + QOFF_OFF),
                       (const unsigned short*)(ws + LISTS2_OFF),
                       (const unsigned char*)(ws + LCNT2_OFF),
                       (const unsigned char*)(ws + ABND_OFF),
                       (const unsigned long long*)(ws + XMT_OFF), ak, av,
                       (unsigned long long*)(ws + MST_OFF));
    hipLaunchKernelGGL(k3_proj, dim3(1024), dim3(384), 0, stream,
                       (const float*)(ws + WPT_OFF), (const float*)(ws + PINV_OFF),
                       (const float*)(ws + POFF_OFF), bp,
                       (const unsigned long long*)(ws + MST_OFF), out);
}

// Round 22
// 85.428 us; speedup vs baseline: 2.0683x; 1.0114x over previous
//
#include <hip/hip_runtime.h>
#include <cstdint>

#define CN (384*1024)          // 393216
#define BCN (16*CN)            // 6291456
#define EPS 1e-5f

typedef float f32x2 __attribute__((ext_vector_type(2)));
typedef float f32x4 __attribute__((ext_vector_type(4)));

// workspace layout (bytes)
#define WPT_OFF   0u           // f32[384][384] = 589824
#define WQB_OFF   589824u      // bf16-as-u16[385][384] (row 384 = zeros), ends 885504
#define QINV_OFF  1179648u
#define QOFF_OFF  (QINV_OFF + 1536u)
#define PINV_OFF  (QINV_OFF + 3072u)
#define POFF_OFF  (QINV_OFF + 4608u)
#define LCNT2_OFF 1187840u     // u8[1024 blocks][64 units], ends 1253376
#define ROWMAX_OFF 1253376u    // f32[384] max_o |bf16(wq[o,r])|, ends 1254912
#define MAXQ_OFF  1254912u     // f32[2] = {max|qi|, max|qo|}
#define XM_OFF    1310720u     // u64[4][16][16][384] n-packed spikes, ends 4456448
#define XMT_OFF   4456448u     // u64[4][16][1024][6] c-packed spikes, ends 7602176
#define LISTS2_OFF 7602176u    // u16[1024][64][24] offsets (idx*3), ends 10747904
#define ABND_OFF  10747904u    // u8[1024][64] quantized unit bounds A*64 (ceil), ends 10813440
#define MST_OFF   XM_OFF       // masked q-spikes u64[col][6]; reuses xm (dead after k1bc)

// ---------------- K01: {LIF + OUTPUT WRITE interleaved by parity} + {prep} ---------
// [0,3072): even -> LIF block (bid>>1), odd -> output-write block (bid>>1).
//           Parity interleave keeps HBM read & write queues concurrently busy.
// [3072,3648): wpT transpose; [3648,4224): wqb bf16 transpose;
// [4224]: consts + maxq + zero row; [4225,4231): rowmax.
__global__ __launch_bounds__(256) void k01_lif_prep(const float* __restrict__ x,
                                                    const float* __restrict__ wq,
                                                    const float* __restrict__ wp,
                                                    const float* __restrict__ qg,
                                                    const float* __restrict__ qb,
                                                    const float* __restrict__ qm,
                                                    const float* __restrict__ qv,
                                                    const float* __restrict__ pg,
                                                    const float* __restrict__ pb,
                                                    const float* __restrict__ pm,
                                                    const float* __restrict__ pv,
                                                    const float* __restrict__ bp,
                                                    unsigned long long* __restrict__ xm,
                                                    char* __restrict__ ws,
                                                    float* __restrict__ out) {
    if (blockIdx.x < 3072) {
        if ((blockIdx.x & 1) == 0) {
            // ---- LIF role: wave = (b,c), 16 g x 4 t deep independent loads ----
            const int lifb = blockIdx.x >> 1;           // 0..1535
            const int wv   = threadIdx.x >> 6;
            const int lane = threadIdx.x & 63;
            const int pid  = lifb * 4 + wv;             // 0..6143 = b*384 + c
            const int b = pid / 384, c = pid % 384;
            const float* xp = x + (size_t)b * CN + (size_t)c * 1024 + lane;
            float v[16];
            #pragma unroll
            for (int g = 0; g < 16; ++g) v[g] = 0.f;
            #pragma unroll
            for (int t = 0; t < 4; ++t) {
                float xv[16];
                #pragma unroll
                for (int g = 0; g < 16; ++g)            // 16 independent 256B loads
                    xv[g] = xp[(size_t)t * BCN + g * 64];
                #pragma unroll
                for (int g = 0; g < 16; ++g) {
                    float h = v[g] + (xv[g] - v[g]) * 0.5f;  // v + (x - v)/tau
                    bool s = (h >= 1.0f);
                    unsigned long long m = __ballot(s);
                    v[g] = s ? 0.f : h;
                    if (lane == 0) xm[(((size_t)t * 16 + b) * 16 + g) * 384 + c] = m;
                }
            }
        } else {
            // ---- write role: rows [w2*16, w2*16+16) of out[t][b][o][n] ----
            __shared__ float sc0[16];
            const int w2 = blockIdx.x >> 1;             // 0..1535
            if (threadIdx.x < 16) {
                int o = (w2 * 16 + threadIdx.x) % 384;
                float pi = pg[o] / sqrtf(pv[o] + EPS);
                float po = pb[o] - pm[o] * pi;
                sc0[threadIdx.x] = bp[o] * pi + po;     // value when GEMM2 input == 0
            }
            __syncthreads();
            f32x4* ob = (f32x4*)out + (size_t)w2 * 4096;
            #pragma unroll
            for (int k = 0; k < 16; ++k) {
                float vv = sc0[k];
                __builtin_nontemporal_store((f32x4){vv, vv, vv, vv},
                                            ob + k * 256 + threadIdx.x);
            }
        }
        return;
    }
    if (blockIdx.x < 3648) {
        int i = (blockIdx.x - 3072) * 256 + threadIdx.x;   // 0..147455
        int o = i / 384, c = i % 384;                      // read coalesced over c
        ((float*)(ws + WPT_OFF))[c * 384 + o] = wp[o * 384 + c];
        return;
    }
    if (blockIdx.x < 4224) {
        int j = (blockIdx.x - 3648) * 256 + threadIdx.x;   // 0..147455
        int o = j / 384, r = j % 384;                      // read coalesced over r
        unsigned u = __float_as_uint(wq[o * 384 + r]);
        unsigned short v = (unsigned short)((u + 0x7fffu + ((u >> 16) & 1u)) >> 16);
        ((unsigned short*)(ws + WQB_OFF))[r * 384 + o] = v;  // rne bf16, scattered store
        return;
    }
    if (blockIdx.x == 4224) {
        __shared__ float smi[256], smo[256];
        float mi = 0.f, mo = 0.f;
        for (int i = threadIdx.x; i < 384; i += 256) {
            float qi = qg[i] / sqrtf(qv[i] + EPS);
            ((float*)(ws + QINV_OFF))[i] = qi;
            float qov = qb[i] - qm[i] * qi;
            ((float*)(ws + QOFF_OFF))[i] = qov;
            float pi = pg[i] / sqrtf(pv[i] + EPS);
            ((float*)(ws + PINV_OFF))[i] = pi;
            ((float*)(ws + POFF_OFF))[i] = pb[i] - pm[i] * pi;
            ((unsigned short*)(ws + WQB_OFF))[384 * 384 + i] = 0;   // zero row 384
            mi = fmaxf(mi, fabsf(qi));
            mo = fmaxf(mo, fabsf(qov));
        }
        smi[threadIdx.x] = mi; smo[threadIdx.x] = mo;
        __syncthreads();
        for (int s = 128; s > 0; s >>= 1) {
            if (threadIdx.x < s) {
                smi[threadIdx.x] = fmaxf(smi[threadIdx.x], smi[threadIdx.x + s]);
                smo[threadIdx.x] = fmaxf(smo[threadIdx.x], smo[threadIdx.x + s]);
            }
            __syncthreads();
        }
        if (threadIdx.x == 0) {
            ((float*)(ws + MAXQ_OFF))[0] = smi[0];
            ((float*)(ws + MAXQ_OFF))[1] = smo[0];
        }
        return;
    }
    {
        // rowmax: 6 blocks; block covers r in [rb*64, rb*64+64); coalesced reads
        __shared__ float sm2[4][64];
        const int rb = blockIdx.x - 4225;               // 0..5
        const int lane = threadIdx.x & 63;
        const int wv = threadIdx.x >> 6;                // 0..3, 96 o's each
        const int r = rb * 64 + lane;
        float m = 0.f;
        for (int o = wv * 96; o < wv * 96 + 96; ++o) {
            unsigned u = __float_as_uint(wq[(size_t)o * 384 + r]);
            unsigned bbits = (u + 0x7fffu + ((u >> 16) & 1u)) >> 16;   // rne bf16
            m = fmaxf(m, __uint_as_float((bbits & 0x7fffu) << 16));    // |bf16|
        }
        sm2[wv][lane] = m;
        __syncthreads();
        if (wv == 0) {
            float r0 = fmaxf(fmaxf(sm2[0][lane], sm2[1][lane]),
                             fmaxf(sm2[2][lane], sm2[3][lane]));
            ((float*)(ws + ROWMAX_OFF))[r] = r0;
        }
    }
}

// ---------------- K1bc: fused bit-transpose + offset-list + unit-bound build -------
__global__ __launch_bounds__(256) void k1bc(const unsigned long long* __restrict__ xm,
                                            const float* __restrict__ rowmaxp,
                                            const float* __restrict__ maxqp,
                                            unsigned long long* __restrict__ xmT,
                                            unsigned short* __restrict__ lists2,
                                            unsigned char* __restrict__ lcnt2,
                                            unsigned char* __restrict__ abnd) {
    int wid  = (blockIdx.x * 256 + threadIdx.x) >> 6;   // 0..1023 = tb*16+g
    int lane = threadIdx.x & 63;
    int g  = wid & 15;
    int tb = wid >> 4;                                  // t*16 + b
    unsigned long long T[6];
    #pragma unroll
    for (int cg = 0; cg < 6; ++cg) {
        unsigned long long W = xm[((size_t)tb * 16 + g) * 384 + cg * 64 + lane];
        unsigned long long colw = 0ull;
        #pragma unroll
        for (int k = 0; k < 64; ++k) {
            unsigned long long bk = __ballot((W >> k) & 1ull);
            if (lane == k) colw = bk;
        }
        T[cg] = colw;
    }
    const int n   = g * 64 + lane;
    const size_t col = ((size_t)tb << 10) + n;
    #pragma unroll
    for (int cg = 0; cg < 6; ++cg) xmT[col * 6 + cg] = T[cg];
    const int blockid = (tb & 15) * 64 + (n >> 4);      // b*64 + n/16
    const int un = (n & 15) * 4 + (tb >> 4);            // (n%16)*4 + t
    unsigned short* lp = lists2 + ((size_t)blockid * 64 + un) * 24;
    int k = 0;
    float S = 0.f;
    #pragma unroll
    for (int cg = 0; cg < 6; ++cg) {
        unsigned long long m = T[cg];
        while (m) {
            int j = __builtin_ctzll(m);
            m &= m - 1;
            S += rowmaxp[cg * 64 + j];
            if (k < 24) lp[k] = (unsigned short)((cg * 64 + j) * 3);
            ++k;
        }
    }
    int kk = k > 24 ? 24 : k;
    for (int i = kk; i < 24; ++i) lp[i] = 1152;         // 384*3 -> zero row (always pad)
    lcnt2[(size_t)blockid * 64 + un] =
        (k > 24) ? 0xFF : (unsigned char)((k + 7) >> 3);
    float A = maxqp[0] * S + maxqp[1];
    int aq = (int)ceilf(A * 64.f);
    abnd[(size_t)blockid * 64 + un] = (unsigned char)(aq > 255 ? 255 : (aq < 0 ? 0 : aq));
}

// ---------------- K2: bound-skip + wave-per-row gather GEMM1 + fused BN/LIF --------
#define BLO(w) __uint_as_float((w) << 16)
#define BHI(w) __uint_as_float((w) & 0xFFFF0000u)
#define PK(w)  ((f32x2){BLO(w), BHI(w)})
#define RL(v, l) ((unsigned)__builtin_amdgcn_readlane((int)(v), (l)))

#define GROW8(W0, W1, W2, W3) do {                                                \
    uint3 d0_ = *(const uint3*)(wqc + ((size_t)((W0) & 0xffffu) << 8) + voff);    \
    uint3 d1_ = *(const uint3*)(wqc + ((size_t)((W0) >> 16) << 8) + voff);        \
    uint3 d2_ = *(const uint3*)(wqc + ((size_t)((W1) & 0xffffu) << 8) + voff);    \
    uint3 d3_ = *(const uint3*)(wqc + ((size_t)((W1) >> 16) << 8) + voff);        \
    uint3 d4_ = *(const uint3*)(wqc + ((size_t)((W2) & 0xffffu) << 8) + voff);    \
    uint3 d5_ = *(const uint3*)(wqc + ((size_t)((W2) >> 16) << 8) + voff);        \
    uint3 d6_ = *(const uint3*)(wqc + ((size_t)((W3) & 0xffffu) << 8) + voff);    \
    uint3 d7_ = *(const uint3*)(wqc + ((size_t)((W3) >> 16) << 8) + voff);        \
    s0 += ((PK(d0_.x) + PK(d1_.x)) + (PK(d2_.x) + PK(d3_.x)))                     \
        + ((PK(d4_.x) + PK(d5_.x)) + (PK(d6_.x) + PK(d7_.x)));                    \
    s1 += ((PK(d0_.y) + PK(d1_.y)) + (PK(d2_.y) + PK(d3_.y)))                     \
        + ((PK(d4_.y) + PK(d5_.y)) + (PK(d6_.y) + PK(d7_.y)));                    \
    s2 += ((PK(d0_.z) + PK(d1_.z)) + (PK(d2_.z) + PK(d3_.z)))                     \
        + ((PK(d4_.z) + PK(d5_.z)) + (PK(d6_.z) + PK(d7_.z)));                    \
} while (0)

__global__ __launch_bounds__(512) void k2_qpath(const char* __restrict__ wqc,
                                                const float* __restrict__ qinv_,
                                                const float* __restrict__ qoff_,
                                                const unsigned short* __restrict__ lists2,
                                                const unsigned char* __restrict__ lcnt2,
                                                const unsigned char* __restrict__ abnd,
                                                const unsigned long long* __restrict__ xmT,
                                                const unsigned char* __restrict__ ak,
                                                const unsigned char* __restrict__ av,
                                                unsigned long long* __restrict__ msT) {
    const int tid  = threadIdx.x;
    const int lane = tid & 63;
    const int w    = tid >> 6;                   // wave 0..7
    const int nt   = blockIdx.x & 63;
    const int b    = blockIdx.x >> 6;
    const int voff = lane * 12;                  // 12B per lane: o = lane*6 + e

    const char* lb = (const char*)lists2 + (size_t)blockIdx.x * 3072 + lane * 48;
    const uint4 L0 = *(const uint4*)lb;           // slots 0-7
    const uint4 L1 = *(const uint4*)(lb + 16);    // slots 8-15
    const uint4 L2 = *(const uint4*)(lb + 32);    // slots 16-23
    const unsigned lcv = *(const unsigned*)((const char*)lcnt2
                          + (size_t)blockIdx.x * 64 + (lane & 15) * 4);
    const unsigned abv = *(const unsigned*)((const char*)abnd
                          + (size_t)blockIdx.x * 64 + (lane & 15) * 4);

    float qi[6], qo[6];
    #pragma unroll
    for (int e = 0; e < 6; ++e) {
        qi[e] = qinv_[lane * 6 + e];
        qo[e] = qoff_[lane * 6 + e];
    }

    #pragma unroll
    for (int i = 0; i < 2; ++i) {
        const int nl = w * 2 + i;                // n-local 0..15 (wave-uniform)
        const int n  = nt * 16 + nl;
        const unsigned abw = RL(abv, nl);        // 4 quantized unit bounds
        float hb = 0.f;
        bool skip = true;
        #pragma unroll
        for (int t = 0; t < 4; ++t) {
            float A = (float)((abw >> (8 * t)) & 0xffu) * 0.015625f + 0.015625f;
            hb = 0.5f * (hb + A);
            skip = skip && (hb < 1.0f);
        }
        if (skip) {                               // provably spike-free column
            if (lane < 6) {
                #pragma unroll
                for (int t = 0; t < 4; ++t)
                    msT[(size_t)(((t * 16 + b) << 10) + n) * 6 + lane] = 0ull;
            }
            continue;
        }
        const unsigned lcw = RL(lcv, nl);        // 4 round-counts (one per t)
        float v[6] = {0.f, 0.f, 0.f, 0.f, 0.f, 0.f};
        #pragma unroll
        for (int t = 0; t < 4; ++t) {
            const int un = nl * 4 + t;           // wave-uniform unit index
            const unsigned r_ = (lcw >> (8 * t)) & 0xffu;
            f32x2 s0 = {0.f, 0.f}, s1 = {0.f, 0.f}, s2 = {0.f, 0.f};
            {
                const unsigned Wa = RL(L0.x, un), Wb = RL(L0.y, un);
                const unsigned Wc = RL(L0.z, un), Wd = RL(L0.w, un);
                const unsigned We = RL(L1.x, un), Wf = RL(L1.y, un);
                const unsigned Wg = RL(L1.z, un), Wh = RL(L1.w, un);
                GROW8(Wa, Wb, Wc, Wd);
                GROW8(We, Wf, Wg, Wh);
            }
            if (r_ == 3u) {
                const unsigned Wa = RL(L2.x, un), Wb = RL(L2.y, un);
                const unsigned Wc = RL(L2.z, un), Wd = RL(L2.w, un);
                GROW8(Wa, Wb, Wc, Wd);
            }
            if (r_ == 0xffu) {                    // overflow fallback (k > 24, ~never)
                const int colf = ((t * 16 + b) << 10) + n;
                const unsigned long long* mp = xmT + (size_t)colf * 6;
                s0 = (f32x2){0.f, 0.f}; s1 = (f32x2){0.f, 0.f}; s2 = (f32x2){0.f, 0.f};
                #pragma unroll
                for (int cg = 0; cg < 6; ++cg) {
                    unsigned long long mm = mp[cg];
                    while (mm) {
                        int j = __builtin_ctzll(mm);
                        mm &= mm - 1;
                        uint3 dd = *(const uint3*)(wqc + (size_t)(cg * 64 + j) * 768 + voff);
                        s0 += PK(dd.x); s1 += PK(dd.y); s2 += PK(dd.z);
                    }
                }
            }
            const int col = ((t * 16 + b) << 10) + n;
            const float val[6] = {s0.x, s0.y, s1.x, s1.y, s2.x, s2.y};
            bool sp[6];
            #pragma unroll
            for (int e = 0; e < 6; ++e) {
                float q = val[e] * qi[e] + qo[e];
                float h = 0.5f * (v[e] + q);     // v + (q - v)/2
                bool s = (h >= 1.0f);
                v[e] = s ? 0.f : h;
                if (s) {                          // rare: attn lookup only on q-spike
                    size_t ix = ((size_t)((t * 16 + b) * 384 + lane * 6 + e) << 10) + n;
                    s = (ak[ix] != 0) && (av[ix] != 0);
                }
                sp[e] = s;
            }
            unsigned long long B0 = __ballot(sp[0]);
            unsigned long long B1 = __ballot(sp[1]);
            unsigned long long B2 = __ballot(sp[2]);
            unsigned long long B3 = __ballot(sp[3]);
            unsigned long long B4 = __ballot(sp[4]);
            unsigned long long B5 = __ballot(sp[5]);
            unsigned long long sel = lane == 0 ? B0 : lane == 1 ? B1 : lane == 2 ? B2
                                   : lane == 3 ? B3 : lane == 4 ? B4 : B5;
            if (lane < 6) msT[(size_t)col * 6 + lane] = sel;
        }
    }
}

// ---------------- K3: slow-path guard (gather GEMM2 only where spikes exist) -------
__global__ __launch_bounds__(384) void k3_proj(const float* __restrict__ wpT,
                                               const float* __restrict__ pinv_,
                                               const float* __restrict__ poff_,
                                               const float* __restrict__ bp,
                                               const unsigned long long* __restrict__ msT,
                                               float* __restrict__ out) {
    __shared__ unsigned int wflag[6];
    const int tid = threadIdx.x;
    const int bid = blockIdx.x;
    const int g = bid & 15, b = (bid >> 4) & 15, t = bid >> 8;
    const unsigned long long* mbase = msT + ((size_t)(t * 16 + b) * 1024 + g * 64) * 6;
    unsigned long long m = mbase[tid];           // 384 words: n-local = tid/6, e = tid%6
    unsigned long long anyb = __ballot(m != 0ull);
    if ((tid & 63) == 0) wflag[tid >> 6] = (anyb != 0ull) ? 1u : 0u;
    __syncthreads();
    unsigned int any = wflag[0] | wflag[1] | wflag[2] | wflag[3] | wflag[4] | wflag[5];
    if (!any) return;                            // k01's optimistic write already correct

    size_t obase = (size_t)(t * 16 + b) * 384;
    float pi = pinv_[tid], po = poff_[tid], bb = bp[tid];
    for (int nl = 0; nl < 64; ++nl) {
        float acc = 0.f;
        #pragma unroll
        for (int u = 0; u < 6; ++u) {
            unsigned long long mm = mbase[nl * 6 + u];
            while (mm) {
                int j = __builtin_ctzll(mm);
                mm &= mm - 1;
                int row = j * 6 + u;
                acc += wpT[(size_t)row * 384 + tid];
            }
        }
        out[(obase + tid) * 1024 + g * 64 + nl] = (acc + bb) * pi + po;
    }
}

extern "C" void kernel_launch(void* const* d_in, const int* in_sizes, int n_in,
                              void* d_out, int out_size, void* d_ws, size_t ws_size,
                              hipStream_t stream) {
    const float* x  = (const float*)d_in[0];
    const unsigned char* ak = (const unsigned char*)d_in[1];
    const unsigned char* av = (const unsigned char*)d_in[2];
    const float* wq = (const float*)d_in[3];
    const float* qg = (const float*)d_in[4];
    const float* qb = (const float*)d_in[5];
    const float* qm = (const float*)d_in[6];
    const float* qv = (const float*)d_in[7];
    const float* wp = (const float*)d_in[8];
    const float* bp = (const float*)d_in[9];
    const float* pg = (const float*)d_in[10];
    const float* pb = (const float*)d_in[11];
    const float* pm = (const float*)d_in[12];
    const float* pv = (const float*)d_in[13];
    char* ws = (char*)d_ws;
    float* out = (float*)d_out;

    hipLaunchKernelGGL(k01_lif_prep, dim3(4231), dim3(256), 0, stream,
                       x, wq, wp, qg, qb, qm, qv, pg, pb, pm, pv, bp,
                       (unsigned long long*)(ws + XM_OFF), ws, out);
    hipLaunchKernelGGL(k1bc, dim3(256), dim3(256), 0, stream,
                       (const unsigned long long*)(ws + XM_OFF),
                       (const float*)(ws + ROWMAX_OFF),
                       (const float*)(ws + MAXQ_OFF),
                       (unsigned long long*)(ws + XMT_OFF),
                       (unsigned short*)(ws + LISTS2_OFF),
                       (unsigned char*)(ws + LCNT2_OFF),
                       (unsigned char*)(ws + ABND_OFF));
    hipLaunchKernelGGL(k2_qpath, dim3(1024), dim3(512), 0, stream,
                       (const char*)(ws + WQB_OFF),
                       (const float*)(ws + QINV_OFF), (const float*)(ws + QOFF_OFF),
                       (const unsigned short*)(ws + LISTS2_OFF),
                       (const unsigned char*)(ws + LCNT2_OFF),
                       (const unsigned char*)(ws + ABND_OFF),
                       (const unsigned long long*)(ws + XMT_OFF), ak, av,
                       (unsigned long long*)(ws + MST_OFF));
    hipLaunchKernelGGL(k3_proj, dim3(1024), dim3(384), 0, stream,
                       (const float*)(ws + WPT_OFF), (const float*)(ws + PINV_OFF),
                       (const float*)(ws + POFF_OFF), bp,
                       (const unsigned long long*)(ws + MST_OFF), out);
}